// Round 8
// baseline (166.486 us; speedup 1.0000x reference)
//
#include <hip/hip_runtime.h>
#include <hip/hip_bf16.h>
#include <math.h>

#define NSP 8000      // 20*20*20 spatial
#define CIN 64
#define LOG2E 1.4426950408889634f

typedef __attribute__((ext_vector_type(8)))  short    bf16x8;
typedef __attribute__((ext_vector_type(4)))  float    f32x4;
typedef __attribute__((ext_vector_type(16))) float    f32x16;
typedef __attribute__((ext_vector_type(8)))  _Float16 f16x8;
typedef __attribute__((ext_vector_type(2)))  __fp16   fp16x2;

__device__ __forceinline__ ushort f2bf(float f) {
    unsigned u = __float_as_uint(f);
    unsigned r = (u + 0x7fffu + ((u >> 16) & 1u)) >> 16;   // RNE
    return (ushort)r;
}

// ---------------------------------------------------------------------------
// wtap[tap][co(80)][ci(64)] bf16  (276,480 B)
// ---------------------------------------------------------------------------
__global__ __launch_bounds__(64) void wtap_kernel(
    const float* __restrict__ wq, const float* __restrict__ wk,
    const float* __restrict__ wv, ushort* __restrict__ wtap)
{
    const int tap = blockIdx.x;        // 0..26
    const int co  = blockIdx.y;        // 0..79
    const int ci  = threadIdx.x;       // 0..63
    float v;
    if (co < 8)       v = wq[(co * 64 + ci) * 27 + tap];
    else if (co < 16) v = wk[((co - 8) * 64 + ci) * 27 + tap];
    else              v = wv[((co - 16) * 64 + ci) * 27 + tap];
    wtap[((size_t)tap * 80 + co) * 64 + ci] = f2bf(v);
}

// ---------------------------------------------------------------------------
// xpad[b][zp(22)][yp(22)][xp(22)][ci(64)] bf16, zero halo. (2,725,888 B)
// xpad[zp][yp][xp] holds x[zp-1][yp-1][xp-1].
// ---------------------------------------------------------------------------
__global__ __launch_bounds__(64) void xpad_kernel(
    const float* __restrict__ x, ushort* __restrict__ xpad)
{
    const int bx  = blockIdx.x;          // 0..967
    const int b   = bx / 484;
    const int rem = bx % 484;
    const int zp  = rem / 22, yp = rem % 22;
    const int ci  = threadIdx.x;
    const bool zy = (zp >= 1 && zp <= 20) && (yp >= 1 && yp <= 20);
    const float* xb = x + ((size_t)b * 64 + ci) * NSP + (zp - 1) * 400 + (yp - 1) * 20;
    ushort* op = xpad + (size_t)b * 681472 + (size_t)(zp * 484 + yp * 22) * 64 + ci;
    for (int xp = 0; xp < 22; ++xp) {
        float v = 0.0f;
        if (zy && xp >= 1 && xp <= 20) v = xb[xp - 1];
        op[xp * 64] = f2bf(v);
    }
}

// ---------------------------------------------------------------------------
// Conv as tap-shift implicit GEMM. 1 wave/block, 16-s tile.
// D[80co][16s] = sum_{tap} W_tap[80co][64ci] @ Xshift[64ci][16s]
// All fragment loads are contiguous 16B/lane (ci-fastest layouts).
// Writes Qt[s][8c] (f16, *log2e), Kt[s][8c], VT[j/16][c][j%16] (f16).
// ---------------------------------------------------------------------------
__global__ __launch_bounds__(64, 4) void conv_mfma_kernel(
    const ushort* __restrict__ xpad, const ushort* __restrict__ wtap,
    const float* __restrict__ bq, const float* __restrict__ bk,
    const float* __restrict__ bv,
    _Float16* __restrict__ Qt, _Float16* __restrict__ Kt, _Float16* __restrict__ VT)
{
    const int l  = threadIdx.x;
    const int bx = blockIdx.x;          // 0..499 (16-s tiles)
    const int b  = blockIdx.y;
    const int s  = bx * 16 + (l & 15);
    const int z  = s / 400;
    const int r0 = s % 400;
    const int y  = r0 / 20;
    const int xx = r0 % 20;
    const int kq = (l >> 4) * 8;        // k-subgroup within 32

    const ushort* xb = xpad + (size_t)b * 681472
                     + (size_t)(z * 484 + y * 22 + xx) * 64 + kq;
    const ushort* wl = wtap + (l & 15) * 64 + kq;

    f32x4 acc[5];
    #pragma unroll
    for (int ct = 0; ct < 5; ++ct) acc[ct] = (f32x4)0.0f;

    for (int dz = 0; dz < 3; ++dz) {
        for (int dy = 0; dy < 3; ++dy) {
            const ushort* xrow = xb + (size_t)(dz * 484 + dy * 22) * 64;
            const ushort* wrow = wl + (size_t)((dz * 3 + dy) * 3) * 80 * 64;
            #pragma unroll
            for (int dx = 0; dx < 3; ++dx) {
                const ushort* xp2 = xrow + dx * 64;
                const bf16x8 b0 = *(const bf16x8*)(xp2);
                const bf16x8 b1 = *(const bf16x8*)(xp2 + 32);
                const ushort* wp = wrow + (size_t)dx * 80 * 64;
                #pragma unroll
                for (int ct = 0; ct < 5; ++ct) {
                    const bf16x8 a0 = *(const bf16x8*)(wp + ct * 16 * 64);
                    const bf16x8 a1 = *(const bf16x8*)(wp + ct * 16 * 64 + 32);
                    acc[ct] = __builtin_amdgcn_mfma_f32_16x16x32_bf16(a0, b0, acc[ct], 0, 0, 0);
                    acc[ct] = __builtin_amdgcn_mfma_f32_16x16x32_bf16(a1, b1, acc[ct], 0, 0, 0);
                }
            }
        }
    }

    // epilogue: D[co = ct*16 + (l>>4)*4 + r][s = l&15]
    #pragma unroll
    for (int ct = 0; ct < 5; ++ct) {
        #pragma unroll
        for (int r = 0; r < 4; ++r) {
            const int co = ct * 16 + (l >> 4) * 4 + r;
            const float v = acc[ct][r];
            if (co < 8)
                Qt[((size_t)b * NSP + s) * 8 + co] = (_Float16)((v + bq[co]) * LOG2E);
            else if (co < 16)
                Kt[((size_t)b * NSP + s) * 8 + (co - 8)] = (_Float16)(v + bk[co - 8]);
            else {
                const int c = co - 16;
                VT[(size_t)b * 512000 + ((size_t)bx * 64 + c) * 16 + (l & 15)] =
                    (_Float16)(v + bv[c]);
            }
        }
    }
}

// ---------------------------------------------------------------------------
// Barrier-free split-j flash attention (8 independent waves, i-tile 32).
// V via VT[j/16][c][j%16]: fully-coalesced 16B/lane fragment loads.
// 1-tile software pipeline on K/V fragment loads; setprio around PV.
// ---------------------------------------------------------------------------
__global__ __launch_bounds__(512, 4) void attn_kernel(
    const _Float16* __restrict__ Qt, const _Float16* __restrict__ Kt,
    const _Float16* __restrict__ VT, float* __restrict__ out)
{
    const int t  = threadIdx.x;
    const int l  = t & 63;
    const int w  = t >> 6;          // j-split 0..7
    const int b  = blockIdx.y;
    const int i0 = blockIdx.x * 32;
    const int il = l & 31;
    const int hi = l >> 5;

    const _Float16* Qtb = Qt + (size_t)b * NSP * 8;
    const _Float16* Ktb = Kt + (size_t)b * NSP * 8;
    const _Float16* VTb = VT + (size_t)b * 512000;

    __shared__ __align__(16) char smem[34816];
    _Float16* p_base = (_Float16*)smem;           // [8][32][36] f16 (18432 B)
    float*    mrg    = (float*)smem;              // [8][32][32] f32 (aliases p)
    float*    mml    = (float*)(smem + 32768);    // [8][32]
    float*    lsm    = (float*)(smem + 33792);    // [8][32]

    _Float16* pw = p_base + w * 1152;             // wave-private P tile

    f16x8 qf = (f16x8)(_Float16)0.0f;
    if (l < 32) qf = *(const f16x8*)&Qtb[(size_t)(i0 + il) * 8];

    float m = -INFINITY, lsum = 0.0f;
    f32x16 acc0 = (f32x16)0.0f, acc1 = (f32x16)0.0f;
    const f32x16 zero16 = (f32x16)0.0f;

#define LOADK(JT, KF) { KF = (f16x8)(_Float16)0.0f;                         \
        if (l < 32) KF = *(const f16x8*)&Ktb[(size_t)((JT) * 32 + il) * 8]; }
#define LOADV(JT, VF) { const int jb = (JT) * 2;                            \
        VF##00 = *(const f16x8*)&VTb[((size_t)(jb + 0) * 64 + il) * 16 + 8 * hi];      \
        VF##01 = *(const f16x8*)&VTb[((size_t)(jb + 1) * 64 + il) * 16 + 8 * hi];      \
        VF##10 = *(const f16x8*)&VTb[((size_t)(jb + 0) * 64 + 32 + il) * 16 + 8 * hi]; \
        VF##11 = *(const f16x8*)&VTb[((size_t)(jb + 1) * 64 + 32 + il) * 16 + 8 * hi]; }

    int jt = w;
    f16x8 kf, vf00, vf01, vf10, vf11;
    LOADK(jt, kf);
    LOADV(jt, vf);

    while (jt < 250) {
        const int jn = jt + 8;
        const bool has = (jn < 250);
        f16x8 kf_n, vn00, vn01, vn10, vn11;
        if (has) { LOADK(jn, kf_n); LOADV(jn, vn); }

        f32x16 sacc = __builtin_amdgcn_mfma_f32_32x32x16_f16(kf, qf, zero16, 0, 0, 0);

        // row max over tile (lane holds 16 j for col i=il)
        float pm = sacc[0];
        #pragma unroll
        for (int r = 1; r < 16; ++r) pm = fmaxf(pm, sacc[r]);
        pm = fmaxf(pm, __shfl_xor(pm, 32));

        // defer-max: rescale only when max grows by > 8 (log2 units)
        if (__any(pm > m + 8.0f)) {
            const float mn = fmaxf(m, pm);
            const float sc = __builtin_amdgcn_exp2f(m - mn);
            #pragma unroll
            for (int r = 0; r < 16; ++r) { acc0[r] *= sc; acc1[r] *= sc; }
            lsum *= sc;
            m = mn;
        }

        float ps = 0.0f;
        #pragma unroll
        for (int r = 0; r < 16; ++r) {
            const float p = __builtin_amdgcn_exp2f(sacc[r] - m);
            sacc[r] = p;
            ps += p;
        }
        ps += __shfl_xor(ps, 32);
        lsum += ps;

        // P -> wave-private LDS: j = 4*hi + 8*g + (r&3), row = i = il
        #pragma unroll
        for (int g = 0; g < 4; ++g) {
            union { fp16x2 h[2]; uint2 u; } pk;
            pk.h[0] = __builtin_amdgcn_cvt_pkrtz(sacc[g * 4 + 0], sacc[g * 4 + 1]);
            pk.h[1] = __builtin_amdgcn_cvt_pkrtz(sacc[g * 4 + 2], sacc[g * 4 + 3]);
            *(uint2*)(pw + il * 36 + g * 8 + hi * 4) = pk.u;
        }
        asm volatile("s_waitcnt lgkmcnt(0)" ::: "memory");
        __builtin_amdgcn_sched_barrier(0);

        // PV: B[k=j][col=i] = P
        __builtin_amdgcn_s_setprio(1);
        {
            const f16x8 pf0 = *(const f16x8*)(pw + il * 36 + 8 * hi);
            acc0 = __builtin_amdgcn_mfma_f32_32x32x16_f16(vf00, pf0, acc0, 0, 0, 0);
            acc1 = __builtin_amdgcn_mfma_f32_32x32x16_f16(vf10, pf0, acc1, 0, 0, 0);
            const f16x8 pf1 = *(const f16x8*)(pw + il * 36 + 16 + 8 * hi);
            acc0 = __builtin_amdgcn_mfma_f32_32x32x16_f16(vf01, pf1, acc0, 0, 0, 0);
            acc1 = __builtin_amdgcn_mfma_f32_32x32x16_f16(vf11, pf1, acc1, 0, 0, 0);
        }
        __builtin_amdgcn_s_setprio(0);

        if (has) {
            kf = kf_n;
            vf00 = vn00; vf01 = vn01; vf10 = vn10; vf11 = vn11;
        }
        jt = jn;
    }
#undef LOADK
#undef LOADV

    // ---- merge 8 per-wave partials ----
    __syncthreads();                      // all waves done with p region
    if (l < 32) mml[w * 32 + il] = m;
    __syncthreads();
    float gm = mml[il];
    #pragma unroll
    for (int ww = 1; ww < 8; ++ww) gm = fmaxf(gm, mml[ww * 32 + il]);
    const float f = __builtin_amdgcn_exp2f(m - gm);
    if (l < 32) lsm[w * 32 + il] = lsum * f;
    #pragma unroll
    for (int r = 0; r < 16; ++r) { acc0[r] *= f; acc1[r] *= f; }

    float* ob = out + (size_t)b * 64 * NSP + i0;

    // ct = 0 (c 0..31)
    #pragma unroll
    for (int r = 0; r < 16; ++r) {
        const int cl = (r & 3) + 8 * (r >> 2) + 4 * hi;
        mrg[w * 1024 + cl * 32 + il] = acc0[r];
    }
    __syncthreads();
    #pragma unroll
    for (int rep = 0; rep < 2; ++rep) {
        const int e = t + rep * 512;
        const int c = e >> 5, i = e & 31;
        float sv = 0.0f, lg = 0.0f;
        #pragma unroll
        for (int ww = 0; ww < 8; ++ww) {
            sv += mrg[ww * 1024 + c * 32 + i];
            lg += lsm[ww * 32 + i];
        }
        float inv;
        asm("v_rcp_f32 %0, %1" : "=v"(inv) : "v"(lg));
        ob[(size_t)c * NSP + i] = sv * inv;
    }
    __syncthreads();                      // protect mrg for ct=1 overwrite

    // ct = 1 (c 32..63)
    #pragma unroll
    for (int r = 0; r < 16; ++r) {
        const int cl = (r & 3) + 8 * (r >> 2) + 4 * hi;
        mrg[w * 1024 + cl * 32 + il] = acc1[r];
    }
    __syncthreads();
    #pragma unroll
    for (int rep = 0; rep < 2; ++rep) {
        const int e = t + rep * 512;
        const int c = e >> 5, i = e & 31;
        float sv = 0.0f, lg = 0.0f;
        #pragma unroll
        for (int ww = 0; ww < 8; ++ww) {
            sv += mrg[ww * 1024 + c * 32 + i];
            lg += lsm[ww * 32 + i];
        }
        float inv;
        asm("v_rcp_f32 %0, %1" : "=v"(inv) : "v"(lg));
        ob[(size_t)(32 + c) * NSP + i] = sv * inv;
    }
}

// ---------------------------------------------------------------------------
extern "C" void kernel_launch(void* const* d_in, const int* in_sizes, int n_in,
                              void* d_out, int out_size, void* d_ws, size_t ws_size,
                              hipStream_t stream) {
    const float* x  = (const float*)d_in[0];
    const float* wq = (const float*)d_in[1];
    const float* bq = (const float*)d_in[2];
    const float* wk = (const float*)d_in[3];
    const float* bk = (const float*)d_in[4];
    const float* wv = (const float*)d_in[5];
    const float* bv = (const float*)d_in[6];
    float* out = (float*)d_out;

    ushort*   wtap = (ushort*)d_ws;                           //       0 .. 276,480
    ushort*   xpad = (ushort*)((char*)d_ws + 278528);         // 2,725,888 B
    _Float16* Qt   = (_Float16*)((char*)d_ws + 3004416);      //   256,000 B [b][s][8c]
    _Float16* Kt   = (_Float16*)((char*)d_ws + 3260416);      //   256,000 B [b][s][8c]
    _Float16* VT   = (_Float16*)((char*)d_ws + 3516416);      // 2,048,000 B [b][j/16][c][j%16]

    wtap_kernel<<<dim3(27, 80), 64, 0, stream>>>(wq, wk, wv, wtap);
    xpad_kernel<<<dim3(968), 64, 0, stream>>>(x, xpad);
    conv_mfma_kernel<<<dim3(500, 2), 64, 0, stream>>>(xpad, wtap, bq, bk, bv, Qt, Kt, VT);
    attn_kernel<<<dim3(250, 2), 512, 0, stream>>>(Qt, Kt, VT, out);
}

// Round 9
// 158.728 us; speedup vs baseline: 1.0489x; 1.0489x over previous
//
#include <hip/hip_runtime.h>
#include <hip/hip_bf16.h>
#include <math.h>

#define NSP 8000      // 20*20*20 spatial
#define CIN 64
#define LOG2E 1.4426950408889634f

typedef __attribute__((ext_vector_type(8)))  short    bf16x8;
typedef __attribute__((ext_vector_type(4)))  float    f32x4;
typedef __attribute__((ext_vector_type(16))) float    f32x16;
typedef __attribute__((ext_vector_type(8)))  _Float16 f16x8;
typedef __attribute__((ext_vector_type(2)))  __fp16   fp16x2;

__device__ __forceinline__ ushort f2bf(float f) {
    unsigned u = __float_as_uint(f);
    unsigned r = (u + 0x7fffu + ((u >> 16) & 1u)) >> 16;   // RNE
    return (ushort)r;
}

// ---------------------------------------------------------------------------
// Fused prep: blocks 0..2159 build wtap[tap][co80][ci64]; blocks 2160..3127
// build xpad[b][22][22][22][ci64] (zero halo; holds x[zp-1][yp-1][xp-1]).
// ---------------------------------------------------------------------------
__global__ __launch_bounds__(64) void prep_kernel(
    const float* __restrict__ wq, const float* __restrict__ wk,
    const float* __restrict__ wv, const float* __restrict__ x,
    ushort* __restrict__ wtap, ushort* __restrict__ xpad)
{
    const int bid = blockIdx.x;
    if (bid < 2160) {
        const int tap = bid / 80;
        const int co  = bid % 80;
        const int ci  = threadIdx.x;
        float v;
        if (co < 8)       v = wq[(co * 64 + ci) * 27 + tap];
        else if (co < 16) v = wk[((co - 8) * 64 + ci) * 27 + tap];
        else              v = wv[((co - 16) * 64 + ci) * 27 + tap];
        wtap[((size_t)tap * 80 + co) * 64 + ci] = f2bf(v);
    } else {
        const int bx  = bid - 2160;        // 0..967
        const int b   = bx / 484;
        const int rem = bx % 484;
        const int zp  = rem / 22, yp = rem % 22;
        const int ci  = threadIdx.x;
        const bool zy = (zp >= 1 && zp <= 20) && (yp >= 1 && yp <= 20);
        const float* xb = x + ((size_t)b * 64 + ci) * NSP + (zp - 1) * 400 + (yp - 1) * 20;
        ushort* op = xpad + (size_t)b * 681472 + (size_t)(zp * 484 + yp * 22) * 64 + ci;
        #pragma unroll
        for (int xp = 0; xp < 22; ++xp) {
            float v = 0.0f;
            if (zy && xp >= 1 && xp <= 20) v = xb[xp - 1];
            op[xp * 64] = f2bf(v);
        }
    }
}

// ---------------------------------------------------------------------------
// Conv tap-shift implicit GEMM, 8 waves/block = 4 s-tiles x 2 tap-splits.
// Split 0: taps 0..13, split 1: taps 14..26; f32 combine via LDS.
// 2000 waves total (~2/SIMD) + L1 A-reuse among the 4 same-split waves.
// Writes Qt[s][8c] (f16, *log2e), Kt[s][8c], VT[j/16][c][j%16] (f16).
// ---------------------------------------------------------------------------
__global__ __launch_bounds__(512, 2) void conv_mfma_kernel(
    const ushort* __restrict__ xpad, const ushort* __restrict__ wtap,
    const float* __restrict__ bq, const float* __restrict__ bk,
    const float* __restrict__ bv,
    _Float16* __restrict__ Qt, _Float16* __restrict__ Kt, _Float16* __restrict__ VT)
{
    const int t  = threadIdx.x;
    const int l  = t & 63;
    const int w  = t >> 6;              // 0..7
    const int sp = w >> 2;              // tap-split 0/1
    const int st = w & 3;               // s-tile within block
    const int bx = blockIdx.x * 4 + st; // 0..499
    const int b  = blockIdx.y;
    const int s  = bx * 16 + (l & 15);
    const int z  = s / 400;
    const int r0 = s % 400;
    const int y  = r0 / 20;
    const int xx = r0 % 20;
    const int kq = (l >> 4) * 8;        // k-subgroup within 32

    const ushort* xb = xpad + (size_t)b * 681472
                     + (size_t)(z * 484 + y * 22 + xx) * 64 + kq;
    const ushort* wl = wtap + (l & 15) * 64 + kq;

    f32x4 acc[5];
    #pragma unroll
    for (int ct = 0; ct < 5; ++ct) acc[ct] = (f32x4)0.0f;

    const int tap0 = sp ? 14 : 0;
    const int tap1 = sp ? 27 : 14;

    for (int tap = tap0; tap < tap1; ++tap) {
        const int dz = tap / 9;
        const int r9 = tap % 9;
        const int dy = r9 / 3;
        const int dx = r9 % 3;
        const ushort* xp2 = xb + (size_t)(dz * 484 + dy * 22 + dx) * 64;
        const bf16x8 b0 = *(const bf16x8*)(xp2);
        const bf16x8 b1 = *(const bf16x8*)(xp2 + 32);
        const ushort* wp = wl + (size_t)tap * 80 * 64;
        #pragma unroll
        for (int ct = 0; ct < 5; ++ct) {
            const bf16x8 a0 = *(const bf16x8*)(wp + ct * 16 * 64);
            const bf16x8 a1 = *(const bf16x8*)(wp + ct * 16 * 64 + 32);
            acc[ct] = __builtin_amdgcn_mfma_f32_16x16x32_bf16(a0, b0, acc[ct], 0, 0, 0);
            acc[ct] = __builtin_amdgcn_mfma_f32_16x16x32_bf16(a1, b1, acc[ct], 0, 0, 0);
        }
    }

    // combine the two tap-splits via LDS
    __shared__ float lacc[4][64][20];
    if (sp == 1) {
        #pragma unroll
        for (int ct = 0; ct < 5; ++ct)
            *(f32x4*)&lacc[st][l][ct * 4] = acc[ct];
    }
    __syncthreads();
    if (sp == 0) {
        #pragma unroll
        for (int ct = 0; ct < 5; ++ct) {
            #pragma unroll
            for (int r = 0; r < 4; ++r) {
                const float v = acc[ct][r] + lacc[st][l][ct * 4 + r];
                const int co = ct * 16 + (l >> 4) * 4 + r;
                if (co < 8)
                    Qt[((size_t)b * NSP + s) * 8 + co] = (_Float16)((v + bq[co]) * LOG2E);
                else if (co < 16)
                    Kt[((size_t)b * NSP + s) * 8 + (co - 8)] = (_Float16)(v + bk[co - 8]);
                else {
                    const int c = co - 16;
                    VT[(size_t)b * 512000 + ((size_t)bx * 64 + c) * 16 + (l & 15)] =
                        (_Float16)(v + bv[c]);
                }
            }
        }
    }
}

// ---------------------------------------------------------------------------
// Barrier-free split-j flash attention (8 independent waves, i-tile 32).
// V via VT[j/16][c][j%16]: fully-coalesced 16B/lane fragment loads.
// 1-tile software pipeline on K/V fragment loads; setprio around PV.
// ---------------------------------------------------------------------------
__global__ __launch_bounds__(512, 4) void attn_kernel(
    const _Float16* __restrict__ Qt, const _Float16* __restrict__ Kt,
    const _Float16* __restrict__ VT, float* __restrict__ out)
{
    const int t  = threadIdx.x;
    const int l  = t & 63;
    const int w  = t >> 6;          // j-split 0..7
    const int b  = blockIdx.y;
    const int i0 = blockIdx.x * 32;
    const int il = l & 31;
    const int hi = l >> 5;

    const _Float16* Qtb = Qt + (size_t)b * NSP * 8;
    const _Float16* Ktb = Kt + (size_t)b * NSP * 8;
    const _Float16* VTb = VT + (size_t)b * 512000;

    __shared__ __align__(16) char smem[34816];
    _Float16* p_base = (_Float16*)smem;           // [8][32][36] f16 (18432 B)
    float*    mrg    = (float*)smem;              // [8][32][32] f32 (aliases p)
    float*    mml    = (float*)(smem + 32768);    // [8][32]
    float*    lsm    = (float*)(smem + 33792);    // [8][32]

    _Float16* pw = p_base + w * 1152;             // wave-private P tile

    f16x8 qf = (f16x8)(_Float16)0.0f;
    if (l < 32) qf = *(const f16x8*)&Qtb[(size_t)(i0 + il) * 8];

    float m = -INFINITY, lsum = 0.0f;
    f32x16 acc0 = (f32x16)0.0f, acc1 = (f32x16)0.0f;
    const f32x16 zero16 = (f32x16)0.0f;

#define LOADK(JT, KF) { KF = (f16x8)(_Float16)0.0f;                         \
        if (l < 32) KF = *(const f16x8*)&Ktb[(size_t)((JT) * 32 + il) * 8]; }
#define LOADV(JT, VF) { const int jb = (JT) * 2;                            \
        VF##00 = *(const f16x8*)&VTb[((size_t)(jb + 0) * 64 + il) * 16 + 8 * hi];      \
        VF##01 = *(const f16x8*)&VTb[((size_t)(jb + 1) * 64 + il) * 16 + 8 * hi];      \
        VF##10 = *(const f16x8*)&VTb[((size_t)(jb + 0) * 64 + 32 + il) * 16 + 8 * hi]; \
        VF##11 = *(const f16x8*)&VTb[((size_t)(jb + 1) * 64 + 32 + il) * 16 + 8 * hi]; }

    int jt = w;
    f16x8 kf, vf00, vf01, vf10, vf11;
    LOADK(jt, kf);
    LOADV(jt, vf);

    while (jt < 250) {
        const int jn = jt + 8;
        const bool has = (jn < 250);
        f16x8 kf_n, vn00, vn01, vn10, vn11;
        if (has) { LOADK(jn, kf_n); LOADV(jn, vn); }

        f32x16 sacc = __builtin_amdgcn_mfma_f32_32x32x16_f16(kf, qf, zero16, 0, 0, 0);

        // row max over tile (lane holds 16 j for col i=il)
        float pm = sacc[0];
        #pragma unroll
        for (int r = 1; r < 16; ++r) pm = fmaxf(pm, sacc[r]);
        pm = fmaxf(pm, __shfl_xor(pm, 32));

        // defer-max: rescale only when max grows by > 8 (log2 units)
        if (__any(pm > m + 8.0f)) {
            const float mn = fmaxf(m, pm);
            const float sc = __builtin_amdgcn_exp2f(m - mn);
            #pragma unroll
            for (int r = 0; r < 16; ++r) { acc0[r] *= sc; acc1[r] *= sc; }
            lsum *= sc;
            m = mn;
        }

        float ps = 0.0f;
        #pragma unroll
        for (int r = 0; r < 16; ++r) {
            const float p = __builtin_amdgcn_exp2f(sacc[r] - m);
            sacc[r] = p;
            ps += p;
        }
        ps += __shfl_xor(ps, 32);
        lsum += ps;

        // P -> wave-private LDS: j = 4*hi + 8*g + (r&3), row = i = il
        #pragma unroll
        for (int g = 0; g < 4; ++g) {
            union { fp16x2 h[2]; uint2 u; } pk;
            pk.h[0] = __builtin_amdgcn_cvt_pkrtz(sacc[g * 4 + 0], sacc[g * 4 + 1]);
            pk.h[1] = __builtin_amdgcn_cvt_pkrtz(sacc[g * 4 + 2], sacc[g * 4 + 3]);
            *(uint2*)(pw + il * 36 + g * 8 + hi * 4) = pk.u;
        }
        asm volatile("s_waitcnt lgkmcnt(0)" ::: "memory");
        __builtin_amdgcn_sched_barrier(0);

        // PV: B[k=j][col=i] = P
        __builtin_amdgcn_s_setprio(1);
        {
            const f16x8 pf0 = *(const f16x8*)(pw + il * 36 + 8 * hi);
            acc0 = __builtin_amdgcn_mfma_f32_32x32x16_f16(vf00, pf0, acc0, 0, 0, 0);
            acc1 = __builtin_amdgcn_mfma_f32_32x32x16_f16(vf10, pf0, acc1, 0, 0, 0);
            const f16x8 pf1 = *(const f16x8*)(pw + il * 36 + 16 + 8 * hi);
            acc0 = __builtin_amdgcn_mfma_f32_32x32x16_f16(vf01, pf1, acc0, 0, 0, 0);
            acc1 = __builtin_amdgcn_mfma_f32_32x32x16_f16(vf11, pf1, acc1, 0, 0, 0);
        }
        __builtin_amdgcn_s_setprio(0);

        if (has) {
            kf = kf_n;
            vf00 = vn00; vf01 = vn01; vf10 = vn10; vf11 = vn11;
        }
        jt = jn;
    }
#undef LOADK
#undef LOADV

    // ---- merge 8 per-wave partials ----
    __syncthreads();                      // all waves done with p region
    if (l < 32) mml[w * 32 + il] = m;
    __syncthreads();
    float gm = mml[il];
    #pragma unroll
    for (int ww = 1; ww < 8; ++ww) gm = fmaxf(gm, mml[ww * 32 + il]);
    const float f = __builtin_amdgcn_exp2f(m - gm);
    if (l < 32) lsm[w * 32 + il] = lsum * f;
    #pragma unroll
    for (int r = 0; r < 16; ++r) { acc0[r] *= f; acc1[r] *= f; }

    float* ob = out + (size_t)b * 64 * NSP + i0;

    // ct = 0 (c 0..31)
    #pragma unroll
    for (int r = 0; r < 16; ++r) {
        const int cl = (r & 3) + 8 * (r >> 2) + 4 * hi;
        mrg[w * 1024 + cl * 32 + il] = acc0[r];
    }
    __syncthreads();
    #pragma unroll
    for (int rep = 0; rep < 2; ++rep) {
        const int e = t + rep * 512;
        const int c = e >> 5, i = e & 31;
        float sv = 0.0f, lg = 0.0f;
        #pragma unroll
        for (int ww = 0; ww < 8; ++ww) {
            sv += mrg[ww * 1024 + c * 32 + i];
            lg += lsm[ww * 32 + i];
        }
        float inv;
        asm("v_rcp_f32 %0, %1" : "=v"(inv) : "v"(lg));
        ob[(size_t)c * NSP + i] = sv * inv;
    }
    __syncthreads();                      // protect mrg for ct=1 overwrite

    // ct = 1 (c 32..63)
    #pragma unroll
    for (int r = 0; r < 16; ++r) {
        const int cl = (r & 3) + 8 * (r >> 2) + 4 * hi;
        mrg[w * 1024 + cl * 32 + il] = acc1[r];
    }
    __syncthreads();
    #pragma unroll
    for (int rep = 0; rep < 2; ++rep) {
        const int e = t + rep * 512;
        const int c = e >> 5, i = e & 31;
        float sv = 0.0f, lg = 0.0f;
        #pragma unroll
        for (int ww = 0; ww < 8; ++ww) {
            sv += mrg[ww * 1024 + c * 32 + i];
            lg += lsm[ww * 32 + i];
        }
        float inv;
        asm("v_rcp_f32 %0, %1" : "=v"(inv) : "v"(lg));
        ob[(size_t)(32 + c) * NSP + i] = sv * inv;
    }
}

// ---------------------------------------------------------------------------
extern "C" void kernel_launch(void* const* d_in, const int* in_sizes, int n_in,
                              void* d_out, int out_size, void* d_ws, size_t ws_size,
                              hipStream_t stream) {
    const float* x  = (const float*)d_in[0];
    const float* wq = (const float*)d_in[1];
    const float* bq = (const float*)d_in[2];
    const float* wk = (const float*)d_in[3];
    const float* bk = (const float*)d_in[4];
    const float* wv = (const float*)d_in[5];
    const float* bv = (const float*)d_in[6];
    float* out = (float*)d_out;

    ushort*   wtap = (ushort*)d_ws;                           //       0 .. 276,480
    ushort*   xpad = (ushort*)((char*)d_ws + 278528);         // 2,725,888 B
    _Float16* Qt   = (_Float16*)((char*)d_ws + 3004416);      //   256,000 B [b][s][8c]
    _Float16* Kt   = (_Float16*)((char*)d_ws + 3260416);      //   256,000 B [b][s][8c]
    _Float16* VT   = (_Float16*)((char*)d_ws + 3516416);      // 2,048,000 B [b][j/16][c][j%16]

    prep_kernel<<<dim3(3128), 64, 0, stream>>>(wq, wk, wv, x, wtap, xpad);
    conv_mfma_kernel<<<dim3(125, 2), 512, 0, stream>>>(xpad, wtap, bq, bk, bv, Qt, Kt, VT);
    attn_kernel<<<dim3(250, 2), 512, 0, stream>>>(Qt, Kt, VT, out);
}

// Round 10
// 152.561 us; speedup vs baseline: 1.0913x; 1.0404x over previous
//
#include <hip/hip_runtime.h>
#include <hip/hip_bf16.h>
#include <math.h>

#define NSP 8000      // 20*20*20 spatial
#define CIN 64
#define LOG2E 1.4426950408889634f

typedef __attribute__((ext_vector_type(8)))  short    bf16x8;
typedef __attribute__((ext_vector_type(4)))  float    f32x4;
typedef __attribute__((ext_vector_type(16))) float    f32x16;
typedef __attribute__((ext_vector_type(8)))  _Float16 f16x8;
typedef __attribute__((ext_vector_type(2)))  __fp16   fp16x2;

__device__ __forceinline__ ushort f2bf(float f) {
    unsigned u = __float_as_uint(f);
    unsigned r = (u + 0x7fffu + ((u >> 16) & 1u)) >> 16;   // RNE
    return (ushort)r;
}

// ---------------------------------------------------------------------------
// Fused prep: blocks 0..2159 build wtap[tap][co80][ci64]; blocks 2160..3127
// build xpad[b][22][22][22][ci64] (zero halo; holds x[zp-1][yp-1][xp-1]).
// ---------------------------------------------------------------------------
__global__ __launch_bounds__(64) void prep_kernel(
    const float* __restrict__ wq, const float* __restrict__ wk,
    const float* __restrict__ wv, const float* __restrict__ x,
    ushort* __restrict__ wtap, ushort* __restrict__ xpad)
{
    const int bid = blockIdx.x;
    if (bid < 2160) {
        const int tap = bid / 80;
        const int co  = bid % 80;
        const int ci  = threadIdx.x;
        float v;
        if (co < 8)       v = wq[(co * 64 + ci) * 27 + tap];
        else if (co < 16) v = wk[((co - 8) * 64 + ci) * 27 + tap];
        else              v = wv[((co - 16) * 64 + ci) * 27 + tap];
        wtap[((size_t)tap * 80 + co) * 64 + ci] = f2bf(v);
    } else {
        const int bx  = bid - 2160;        // 0..967
        const int b   = bx / 484;
        const int rem = bx % 484;
        const int zp  = rem / 22, yp = rem % 22;
        const int ci  = threadIdx.x;
        const bool zy = (zp >= 1 && zp <= 20) && (yp >= 1 && yp <= 20);
        const float* xb = x + ((size_t)b * 64 + ci) * NSP + (zp - 1) * 400 + (yp - 1) * 20;
        ushort* op = xpad + (size_t)b * 681472 + (size_t)(zp * 484 + yp * 22) * 64 + ci;
        #pragma unroll
        for (int xp = 0; xp < 22; ++xp) {
            float v = 0.0f;
            if (zy && xp >= 1 && xp <= 20) v = xb[xp - 1];
            op[xp * 64] = f2bf(v);
        }
    }
}

// ---------------------------------------------------------------------------
// Conv tap-shift implicit GEMM, 8 waves/block = 2 s-tiles x 4 tap-splits.
// Splits: taps {0-6, 7-13, 14-20, 21-26}; f32 combine via LDS.
// 4000 waves (~4/SIMD) for latency hiding.
// Writes Qt[s][8c] (f16, *log2e), Kt[s][8c], VT[j/16][c][j%16] (f16).
// ---------------------------------------------------------------------------
__global__ __launch_bounds__(512, 2) void conv_mfma_kernel(
    const ushort* __restrict__ xpad, const ushort* __restrict__ wtap,
    const float* __restrict__ bq, const float* __restrict__ bk,
    const float* __restrict__ bv,
    _Float16* __restrict__ Qt, _Float16* __restrict__ Kt, _Float16* __restrict__ VT)
{
    const int t  = threadIdx.x;
    const int l  = t & 63;
    const int w  = t >> 6;              // 0..7
    const int st = w & 1;               // s-tile within block
    const int sp = w >> 1;              // tap-split 0..3
    const int bx = blockIdx.x * 2 + st; // 0..499
    const int b  = blockIdx.y;
    const int s  = bx * 16 + (l & 15);
    const int z  = s / 400;
    const int r0 = s % 400;
    const int y  = r0 / 20;
    const int xx = r0 % 20;
    const int kq = (l >> 4) * 8;        // k-subgroup within 32

    const ushort* xb = xpad + (size_t)b * 681472
                     + (size_t)(z * 484 + y * 22 + xx) * 64 + kq;
    const ushort* wl = wtap + (l & 15) * 64 + kq;

    f32x4 acc[5];
    #pragma unroll
    for (int ct = 0; ct < 5; ++ct) acc[ct] = (f32x4)0.0f;

    const int tap0 = sp * 7;
    const int tap1 = (sp == 3) ? 27 : (tap0 + 7);

    for (int tap = tap0; tap < tap1; ++tap) {
        const int dz = tap / 9;
        const int r9 = tap % 9;
        const int dy = r9 / 3;
        const int dx = r9 % 3;
        const ushort* xp2 = xb + (size_t)(dz * 484 + dy * 22 + dx) * 64;
        const bf16x8 b0 = *(const bf16x8*)(xp2);
        const bf16x8 b1 = *(const bf16x8*)(xp2 + 32);
        const ushort* wp = wl + (size_t)tap * 80 * 64;
        #pragma unroll
        for (int ct = 0; ct < 5; ++ct) {
            const bf16x8 a0 = *(const bf16x8*)(wp + ct * 16 * 64);
            const bf16x8 a1 = *(const bf16x8*)(wp + ct * 16 * 64 + 32);
            acc[ct] = __builtin_amdgcn_mfma_f32_16x16x32_bf16(a0, b0, acc[ct], 0, 0, 0);
            acc[ct] = __builtin_amdgcn_mfma_f32_16x16x32_bf16(a1, b1, acc[ct], 0, 0, 0);
        }
    }

    // combine the four tap-splits via LDS
    __shared__ float lacc[3][2][64][20];
    if (sp > 0) {
        #pragma unroll
        for (int ct = 0; ct < 5; ++ct)
            *(f32x4*)&lacc[sp - 1][st][l][ct * 4] = acc[ct];
    }
    __syncthreads();
    if (sp == 0) {
        #pragma unroll
        for (int ct = 0; ct < 5; ++ct) {
            #pragma unroll
            for (int r = 0; r < 4; ++r) {
                const float v = acc[ct][r] + lacc[0][st][l][ct * 4 + r]
                             + lacc[1][st][l][ct * 4 + r] + lacc[2][st][l][ct * 4 + r];
                const int co = ct * 16 + (l >> 4) * 4 + r;
                if (co < 8)
                    Qt[((size_t)b * NSP + s) * 8 + co] = (_Float16)((v + bq[co]) * LOG2E);
                else if (co < 16)
                    Kt[((size_t)b * NSP + s) * 8 + (co - 8)] = (_Float16)(v + bk[co - 8]);
                else {
                    const int c = co - 16;
                    VT[(size_t)b * 512000 + ((size_t)bx * 64 + c) * 16 + (l & 15)] =
                        (_Float16)(v + bv[c]);
                }
            }
        }
    }
}

// ---------------------------------------------------------------------------
// Barrier-free split-j flash attention (8 independent waves, i-tile 32).
// V via VT[j/16][c][j%16] (coalesced). P redistribution fully in-register:
// 8x cvt_pkrtz + 4x v_permlane32_swap_b32 build both PV B-frags — no LDS,
// no waitcnt, no cross-lane shuffles in the steady-state loop.
// ---------------------------------------------------------------------------
__global__ __launch_bounds__(512, 2) void attn_kernel(
    const _Float16* __restrict__ Qt, const _Float16* __restrict__ Kt,
    const _Float16* __restrict__ VT, float* __restrict__ out)
{
    const int t  = threadIdx.x;
    const int l  = t & 63;
    const int w  = t >> 6;          // j-split 0..7
    const int b  = blockIdx.y;
    const int i0 = blockIdx.x * 32;
    const int il = l & 31;
    const int hi = l >> 5;

    const _Float16* Qtb = Qt + (size_t)b * NSP * 8;
    const _Float16* Ktb = Kt + (size_t)b * NSP * 8;
    const _Float16* VTb = VT + (size_t)b * 512000;

    __shared__ __align__(16) char smem[34816];
    float* mrg = (float*)smem;              // [8][32][32] f32
    float* mml = (float*)(smem + 32768);    // [8][32]
    float* lsm = (float*)(smem + 33792);    // [8][32]

    f16x8 qf = (f16x8)(_Float16)0.0f;
    if (l < 32) qf = *(const f16x8*)&Qtb[(size_t)(i0 + il) * 8];

    float m = -INFINITY, lsum = 0.0f;       // per (i, half): lsum covers own 16 j's
    f32x16 acc0 = (f32x16)0.0f, acc1 = (f32x16)0.0f;
    const f32x16 zero16 = (f32x16)0.0f;

#define LOADK(JT, KF) { KF = (f16x8)(_Float16)0.0f;                         \
        if (l < 32) KF = *(const f16x8*)&Ktb[(size_t)((JT) * 32 + il) * 8]; }
#define LOADV(JT, VF) { const int jb = (JT) * 2;                            \
        VF##00 = *(const f16x8*)&VTb[((size_t)(jb + 0) * 64 + il) * 16 + 8 * hi];      \
        VF##01 = *(const f16x8*)&VTb[((size_t)(jb + 1) * 64 + il) * 16 + 8 * hi];      \
        VF##10 = *(const f16x8*)&VTb[((size_t)(jb + 0) * 64 + 32 + il) * 16 + 8 * hi]; \
        VF##11 = *(const f16x8*)&VTb[((size_t)(jb + 1) * 64 + 32 + il) * 16 + 8 * hi]; }

    int jt = w;
    f16x8 kf, vf00, vf01, vf10, vf11;
    LOADK(jt, kf);
    LOADV(jt, vf);

    while (jt < 250) {
        const int jn = jt + 8;
        const bool has = (jn < 250);
        f16x8 kf_n, vn00, vn01, vn10, vn11;
        if (has) { LOADK(jn, kf_n); LOADV(jn, vn); }

        f32x16 sacc = __builtin_amdgcn_mfma_f32_32x32x16_f16(kf, qf, zero16, 0, 0, 0);

        // per-half max over own 16 j's (pair tree, depth 4)
        float x0 = fmaxf(sacc[0], sacc[1]),   x1 = fmaxf(sacc[2], sacc[3]);
        float x2 = fmaxf(sacc[4], sacc[5]),   x3 = fmaxf(sacc[6], sacc[7]);
        float x4 = fmaxf(sacc[8], sacc[9]),   x5 = fmaxf(sacc[10], sacc[11]);
        float x6 = fmaxf(sacc[12], sacc[13]), x7 = fmaxf(sacc[14], sacc[15]);
        float pm = fmaxf(fmaxf(fmaxf(x0, x1), fmaxf(x2, x3)),
                         fmaxf(fmaxf(x4, x5), fmaxf(x6, x7)));

        // defer-max: rescale only when max grows by > 8 (log2 units).
        // cross-half sync of m happens only inside this rare branch.
        if (__any(pm > m + 8.0f)) {
            pm = fmaxf(pm, __shfl_xor(pm, 32));
            const float mn = fmaxf(m, pm);
            const float sc = __builtin_amdgcn_exp2f(m - mn);
            #pragma unroll
            for (int r = 0; r < 16; ++r) { acc0[r] *= sc; acc1[r] *= sc; }
            lsum *= sc;
            m = mn;
        }

        #pragma unroll
        for (int r = 0; r < 16; ++r)
            sacc[r] = __builtin_amdgcn_exp2f(sacc[r] - m);
        // pairwise sum tree (per-half lsum)
        {
            float s0 = (sacc[0] + sacc[1]) + (sacc[2] + sacc[3]);
            float s1 = (sacc[4] + sacc[5]) + (sacc[6] + sacc[7]);
            float s2 = (sacc[8] + sacc[9]) + (sacc[10] + sacc[11]);
            float s3 = (sacc[12] + sacc[13]) + (sacc[14] + sacc[15]);
            lsum += (s0 + s1) + (s2 + s3);
        }

        // pack P to f16 pairs: w_k covers j = (rr&3)+8*(rr>>2)+4*hi for rr=2k,2k+1
        unsigned w0, w1, w2, w3, w4, w5, w6, w7;
        {
            union { fp16x2 h; unsigned u; } c;
            c.h = __builtin_amdgcn_cvt_pkrtz(sacc[0],  sacc[1]);  w0 = c.u;
            c.h = __builtin_amdgcn_cvt_pkrtz(sacc[2],  sacc[3]);  w1 = c.u;
            c.h = __builtin_amdgcn_cvt_pkrtz(sacc[4],  sacc[5]);  w2 = c.u;
            c.h = __builtin_amdgcn_cvt_pkrtz(sacc[6],  sacc[7]);  w3 = c.u;
            c.h = __builtin_amdgcn_cvt_pkrtz(sacc[8],  sacc[9]);  w4 = c.u;
            c.h = __builtin_amdgcn_cvt_pkrtz(sacc[10], sacc[11]); w5 = c.u;
            c.h = __builtin_amdgcn_cvt_pkrtz(sacc[12], sacc[13]); w6 = c.u;
            c.h = __builtin_amdgcn_cvt_pkrtz(sacc[14], sacc[15]); w7 = c.u;
        }
        // in-register half-swap: builds B-frag words for both lane-halves
        unsigned A0 = w0, A2 = w2, A1 = w1, A3 = w3;
        unsigned B0 = w4, B2 = w6, B1 = w5, B3 = w7;
        asm("v_permlane32_swap_b32 %0, %1" : "+v"(A0), "+v"(A2));
        asm("v_permlane32_swap_b32 %0, %1" : "+v"(A1), "+v"(A3));
        asm("v_permlane32_swap_b32 %0, %1" : "+v"(B0), "+v"(B2));
        asm("v_permlane32_swap_b32 %0, %1" : "+v"(B1), "+v"(B3));
        union { unsigned u[4]; f16x8 v; } pf0u, pf1u;
        pf0u.u[0] = A0; pf0u.u[1] = A1; pf0u.u[2] = A2; pf0u.u[3] = A3;
        pf1u.u[0] = B0; pf1u.u[1] = B1; pf1u.u[2] = B2; pf1u.u[3] = B3;

        __builtin_amdgcn_s_setprio(1);
        acc0 = __builtin_amdgcn_mfma_f32_32x32x16_f16(vf00, pf0u.v, acc0, 0, 0, 0);
        acc1 = __builtin_amdgcn_mfma_f32_32x32x16_f16(vf10, pf0u.v, acc1, 0, 0, 0);
        acc0 = __builtin_amdgcn_mfma_f32_32x32x16_f16(vf01, pf1u.v, acc0, 0, 0, 0);
        acc1 = __builtin_amdgcn_mfma_f32_32x32x16_f16(vf11, pf1u.v, acc1, 0, 0, 0);
        __builtin_amdgcn_s_setprio(0);

        if (has) {
            kf = kf_n;
            vf00 = vn00; vf01 = vn01; vf10 = vn10; vf11 = vn11;
        }
        jt = jn;
    }
#undef LOADK
#undef LOADV

    // ---- merge 8 per-wave partials ----
    lsum += __shfl_xor(lsum, 32);         // combine the two half-lane lsums
    if (l < 32) mml[w * 32 + il] = m;     // m is wave-uniform per i
    __syncthreads();
    float gm = mml[il];
    #pragma unroll
    for (int ww = 1; ww < 8; ++ww) gm = fmaxf(gm, mml[ww * 32 + il]);
    const float f = __builtin_amdgcn_exp2f(m - gm);
    if (l < 32) lsm[w * 32 + il] = lsum * f;
    #pragma unroll
    for (int r = 0; r < 16; ++r) { acc0[r] *= f; acc1[r] *= f; }

    float* ob = out + (size_t)b * 64 * NSP + i0;

    // ct = 0 (c 0..31)
    #pragma unroll
    for (int r = 0; r < 16; ++r) {
        const int cl = (r & 3) + 8 * (r >> 2) + 4 * hi;
        mrg[w * 1024 + cl * 32 + il] = acc0[r];
    }
    __syncthreads();
    #pragma unroll
    for (int rep = 0; rep < 2; ++rep) {
        const int e = t + rep * 512;
        const int c = e >> 5, i = e & 31;
        float sv = 0.0f, lg = 0.0f;
        #pragma unroll
        for (int ww = 0; ww < 8; ++ww) {
            sv += mrg[ww * 1024 + c * 32 + i];
            lg += lsm[ww * 32 + i];
        }
        float inv;
        asm("v_rcp_f32 %0, %1" : "=v"(inv) : "v"(lg));
        ob[(size_t)c * NSP + i] = sv * inv;
    }
    __syncthreads();                      // protect mrg for ct=1 overwrite

    // ct = 1 (c 32..63)
    #pragma unroll
    for (int r = 0; r < 16; ++r) {
        const int cl = (r & 3) + 8 * (r >> 2) + 4 * hi;
        mrg[w * 1024 + cl * 32 + il] = acc1[r];
    }
    __syncthreads();
    #pragma unroll
    for (int rep = 0; rep < 2; ++rep) {
        const int e = t + rep * 512;
        const int c = e >> 5, i = e & 31;
        float sv = 0.0f, lg = 0.0f;
        #pragma unroll
        for (int ww = 0; ww < 8; ++ww) {
            sv += mrg[ww * 1024 + c * 32 + i];
            lg += lsm[ww * 32 + i];
        }
        float inv;
        asm("v_rcp_f32 %0, %1" : "=v"(inv) : "v"(lg));
        ob[(size_t)(32 + c) * NSP + i] = sv * inv;
    }
}

// ---------------------------------------------------------------------------
extern "C" void kernel_launch(void* const* d_in, const int* in_sizes, int n_in,
                              void* d_out, int out_size, void* d_ws, size_t ws_size,
                              hipStream_t stream) {
    const float* x  = (const float*)d_in[0];
    const float* wq = (const float*)d_in[1];
    const float* bq = (const float*)d_in[2];
    const float* wk = (const float*)d_in[3];
    const float* bk = (const float*)d_in[4];
    const float* wv = (const float*)d_in[5];
    const float* bv = (const float*)d_in[6];
    float* out = (float*)d_out;

    ushort*   wtap = (ushort*)d_ws;                           //       0 .. 276,480
    ushort*   xpad = (ushort*)((char*)d_ws + 278528);         // 2,725,888 B
    _Float16* Qt   = (_Float16*)((char*)d_ws + 3004416);      //   256,000 B [b][s][8c]
    _Float16* Kt   = (_Float16*)((char*)d_ws + 3260416);      //   256,000 B [b][s][8c]
    _Float16* VT   = (_Float16*)((char*)d_ws + 3516416);      // 2,048,000 B [b][j/16][c][j%16]

    prep_kernel<<<dim3(3128), 64, 0, stream>>>(wq, wk, wv, x, wtap, xpad);
    conv_mfma_kernel<<<dim3(250, 2), 512, 0, stream>>>(xpad, wtap, bq, bk, bv, Qt, Kt, VT);
    attn_kernel<<<dim3(250, 2), 512, 0, stream>>>(Qt, Kt, VT, out);
}

// Round 11
// 143.073 us; speedup vs baseline: 1.1636x; 1.0663x over previous
//
#include <hip/hip_runtime.h>
#include <hip/hip_bf16.h>
#include <math.h>

#define NSP 8000      // 20*20*20 spatial
#define CIN 64
#define LOG2E 1.4426950408889634f

typedef __attribute__((ext_vector_type(8)))  short    bf16x8;
typedef __attribute__((ext_vector_type(4)))  float    f32x4;
typedef __attribute__((ext_vector_type(16))) float    f32x16;
typedef __attribute__((ext_vector_type(8)))  _Float16 f16x8;
typedef __attribute__((ext_vector_type(2)))  __fp16   fp16x2;

__device__ __forceinline__ ushort f2bf(float f) {
    unsigned u = __float_as_uint(f);
    unsigned r = (u + 0x7fffu + ((u >> 16) & 1u)) >> 16;   // RNE
    return (ushort)r;
}

// ---------------------------------------------------------------------------
// Fused prep: blocks 0..2159 build wtap[tap][co80][ci64]; blocks 2160..3127
// build xpad[b][22][22][22][ci64] (zero halo; holds x[zp-1][yp-1][xp-1]).
// ---------------------------------------------------------------------------
__global__ __launch_bounds__(64) void prep_kernel(
    const float* __restrict__ wq, const float* __restrict__ wk,
    const float* __restrict__ wv, const float* __restrict__ x,
    ushort* __restrict__ wtap, ushort* __restrict__ xpad)
{
    const int bid = blockIdx.x;
    if (bid < 2160) {
        const int tap = bid / 80;
        const int co  = bid % 80;
        const int ci  = threadIdx.x;
        float v;
        if (co < 8)       v = wq[(co * 64 + ci) * 27 + tap];
        else if (co < 16) v = wk[((co - 8) * 64 + ci) * 27 + tap];
        else              v = wv[((co - 16) * 64 + ci) * 27 + tap];
        wtap[((size_t)tap * 80 + co) * 64 + ci] = f2bf(v);
    } else {
        const int bx  = bid - 2160;        // 0..967
        const int b   = bx / 484;
        const int rem = bx % 484;
        const int zp  = rem / 22, yp = rem % 22;
        const int ci  = threadIdx.x;
        const bool zy = (zp >= 1 && zp <= 20) && (yp >= 1 && yp <= 20);
        const float* xb = x + ((size_t)b * 64 + ci) * NSP + (zp - 1) * 400 + (yp - 1) * 20;
        ushort* op = xpad + (size_t)b * 681472 + (size_t)(zp * 484 + yp * 22) * 64 + ci;
        #pragma unroll
        for (int xp = 0; xp < 22; ++xp) {
            float v = 0.0f;
            if (zy && xp >= 1 && xp <= 20) v = xb[xp - 1];
            op[xp * 64] = f2bf(v);
        }
    }
}

// ---------------------------------------------------------------------------
// Conv tap-shift implicit GEMM. 8 waves/block = 2 x 32-s tiles x 4 tap-splits.
// Each wave: 32 s (2 MFMA sub-tiles sharing A-frags), taps {0-6,7-13,14-20,21-26}.
// Fully unrolled tap loops -> compiler pipelines loads across taps.
// f32 combine via LDS (60 KB). 2000 waves.
// ---------------------------------------------------------------------------
__global__ __launch_bounds__(512) void conv_mfma_kernel(
    const ushort* __restrict__ xpad, const ushort* __restrict__ wtap,
    const float* __restrict__ bq, const float* __restrict__ bk,
    const float* __restrict__ bv,
    _Float16* __restrict__ Qt, _Float16* __restrict__ Kt, _Float16* __restrict__ VT)
{
    const int t  = threadIdx.x;
    const int l  = t & 63;
    const int w  = t >> 6;              // 0..7
    const int st = w & 1;               // which 32-s half of the 64-s block
    const int sp = w >> 1;              // tap-split 0..3
    const int b  = blockIdx.y;
    const int s0 = blockIdx.x * 64 + st * 32;
    const int kq = (l >> 4) * 8;        // k-subgroup within 32

    const int sA = s0 + (l & 15);
    const int sB = sA + 16;
    const int zA = sA / 400, rA = sA % 400, yA = rA / 20, xA = rA % 20;
    const int zB = sB / 400, rB = sB % 400, yB = rB / 20, xB = rB % 20;

    const ushort* xpb = xpad + (size_t)b * 681472;
    const ushort* xbA = xpb + (size_t)(zA * 484 + yA * 22 + xA) * 64 + kq;
    const ushort* xbB = xpb + (size_t)(zB * 484 + yB * 22 + xB) * 64 + kq;
    const ushort* wl  = wtap + (l & 15) * 64 + kq;

    f32x4 accA[5], accB[5];
    #pragma unroll
    for (int ct = 0; ct < 5; ++ct) { accA[ct] = (f32x4)0.0f; accB[ct] = (f32x4)0.0f; }

#define TAP(TAPI) {                                                          \
        const int tap_ = (TAPI);                                             \
        const int dz_ = tap_ / 9, r9_ = tap_ % 9;                            \
        const int off_ = (dz_ * 484 + (r9_ / 3) * 22 + (r9_ % 3)) * 64;      \
        const bf16x8 bA0 = *(const bf16x8*)(xbA + off_);                     \
        const bf16x8 bA1 = *(const bf16x8*)(xbA + off_ + 32);                \
        const bf16x8 bB0 = *(const bf16x8*)(xbB + off_);                     \
        const bf16x8 bB1 = *(const bf16x8*)(xbB + off_ + 32);                \
        const ushort* wp_ = wl + (size_t)tap_ * 80 * 64;                     \
        _Pragma("unroll") for (int ct = 0; ct < 5; ++ct) {                   \
            const bf16x8 a0 = *(const bf16x8*)(wp_ + ct * 16 * 64);          \
            const bf16x8 a1 = *(const bf16x8*)(wp_ + ct * 16 * 64 + 32);     \
            accA[ct] = __builtin_amdgcn_mfma_f32_16x16x32_bf16(a0, bA0, accA[ct], 0, 0, 0); \
            accA[ct] = __builtin_amdgcn_mfma_f32_16x16x32_bf16(a1, bA1, accA[ct], 0, 0, 0); \
            accB[ct] = __builtin_amdgcn_mfma_f32_16x16x32_bf16(a0, bB0, accB[ct], 0, 0, 0); \
            accB[ct] = __builtin_amdgcn_mfma_f32_16x16x32_bf16(a1, bB1, accB[ct], 0, 0, 0); \
        } }

    if (sp < 3) {
        const int tap0 = sp * 7;
        #pragma unroll
        for (int k = 0; k < 7; ++k) TAP(tap0 + k);
    } else {
        #pragma unroll
        for (int k = 0; k < 6; ++k) TAP(21 + k);
    }
#undef TAP

    // combine the four tap-splits via LDS
    __shared__ float lacc[3][2][2][64][20];   // [sp-1][st][sub][lane][20]
    if (sp > 0) {
        #pragma unroll
        for (int ct = 0; ct < 5; ++ct) {
            *(f32x4*)&lacc[sp - 1][st][0][l][ct * 4] = accA[ct];
            *(f32x4*)&lacc[sp - 1][st][1][l][ct * 4] = accB[ct];
        }
    }
    __syncthreads();
    if (sp == 0) {
        #pragma unroll
        for (int u = 0; u < 2; ++u) {
            const int s  = s0 + u * 16 + (l & 15);
            const int jb = s >> 4;
            #pragma unroll
            for (int ct = 0; ct < 5; ++ct) {
                #pragma unroll
                for (int r = 0; r < 4; ++r) {
                    float v = (u ? accB[ct][r] : accA[ct][r]);
                    v += lacc[0][st][u][l][ct * 4 + r]
                       + lacc[1][st][u][l][ct * 4 + r]
                       + lacc[2][st][u][l][ct * 4 + r];
                    const int co = ct * 16 + (l >> 4) * 4 + r;
                    if (co < 8)
                        Qt[((size_t)b * NSP + s) * 8 + co] = (_Float16)((v + bq[co]) * LOG2E);
                    else if (co < 16)
                        Kt[((size_t)b * NSP + s) * 8 + (co - 8)] = (_Float16)(v + bk[co - 8]);
                    else {
                        const int c = co - 16;
                        VT[(size_t)b * 512000 + ((size_t)jb * 64 + c) * 16 + (l & 15)] =
                            (_Float16)(v + bv[c]);
                    }
                }
            }
        }
    }
}

// ---------------------------------------------------------------------------
// Barrier-free split-j flash attention (8 independent waves, i-tile 32).
// All-in-register softmax: permlane P-redistribution; row-sum via all-ones
// MFMA (acc2 holds sum_j P) -> no VALU sum tree, no lsum bookkeeping.
// ---------------------------------------------------------------------------
__global__ __launch_bounds__(512, 2) void attn_kernel(
    const _Float16* __restrict__ Qt, const _Float16* __restrict__ Kt,
    const _Float16* __restrict__ VT, float* __restrict__ out)
{
    const int t  = threadIdx.x;
    const int l  = t & 63;
    const int w  = t >> 6;          // j-split 0..7
    const int b  = blockIdx.y;
    const int i0 = blockIdx.x * 32;
    const int il = l & 31;
    const int hi = l >> 5;

    const _Float16* Qtb = Qt + (size_t)b * NSP * 8;
    const _Float16* Ktb = Kt + (size_t)b * NSP * 8;
    const _Float16* VTb = VT + (size_t)b * 512000;

    __shared__ __align__(16) char smem[34816];
    float* mrg = (float*)smem;              // [8][32][32] f32
    float* mml = (float*)(smem + 32768);    // [8][32]
    float* lsm = (float*)(smem + 33792);    // [8][32]

    f16x8 qf = (f16x8)(_Float16)0.0f;
    if (l < 32) qf = *(const f16x8*)&Qtb[(size_t)(i0 + il) * 8];

    f16x8 onesf;
    #pragma unroll
    for (int e = 0; e < 8; ++e) onesf[e] = (_Float16)1.0f;

    float m = -INFINITY;
    f32x16 acc0 = (f32x16)0.0f, acc1 = (f32x16)0.0f, acc2 = (f32x16)0.0f;
    const f32x16 zero16 = (f32x16)0.0f;

#define LOADK(JT, KF) { KF = (f16x8)(_Float16)0.0f;                         \
        if (l < 32) KF = *(const f16x8*)&Ktb[(size_t)((JT) * 32 + il) * 8]; }
#define LOADV(JT, VF) { const int jb = (JT) * 2;                            \
        VF##00 = *(const f16x8*)&VTb[((size_t)(jb + 0) * 64 + il) * 16 + 8 * hi];      \
        VF##01 = *(const f16x8*)&VTb[((size_t)(jb + 1) * 64 + il) * 16 + 8 * hi];      \
        VF##10 = *(const f16x8*)&VTb[((size_t)(jb + 0) * 64 + 32 + il) * 16 + 8 * hi]; \
        VF##11 = *(const f16x8*)&VTb[((size_t)(jb + 1) * 64 + 32 + il) * 16 + 8 * hi]; }

    int jt = w;
    f16x8 kf, vf00, vf01, vf10, vf11;
    LOADK(jt, kf);
    LOADV(jt, vf);

    while (jt < 250) {
        const int jn = jt + 8;
        const bool has = (jn < 250);
        f16x8 kf_n, vn00, vn01, vn10, vn11;
        if (has) { LOADK(jn, kf_n); LOADV(jn, vn); }

        f32x16 sacc = __builtin_amdgcn_mfma_f32_32x32x16_f16(kf, qf, zero16, 0, 0, 0);

        // per-half max over own 16 j's via max3 fusion
        float m1 = fmaxf(fmaxf(sacc[0],  sacc[1]),  sacc[2]);
        float m2 = fmaxf(fmaxf(sacc[3],  sacc[4]),  sacc[5]);
        float m3 = fmaxf(fmaxf(sacc[6],  sacc[7]),  sacc[8]);
        float m4 = fmaxf(fmaxf(sacc[9],  sacc[10]), sacc[11]);
        float m5 = fmaxf(fmaxf(sacc[12], sacc[13]), sacc[14]);
        float pm = fmaxf(fmaxf(fmaxf(m1, m2), fmaxf(m3, m4)),
                         fmaxf(m5, sacc[15]));

        // defer-max: rescale only when max grows by > 8 (log2 units)
        if (__any(pm > m + 8.0f)) {
            pm = fmaxf(pm, __shfl_xor(pm, 32));
            const float mn = fmaxf(m, pm);
            const float sc = __builtin_amdgcn_exp2f(m - mn);
            #pragma unroll
            for (int r = 0; r < 16; ++r) {
                acc0[r] *= sc; acc1[r] *= sc; acc2[r] *= sc;
            }
            m = mn;
        }

        #pragma unroll
        for (int r = 0; r < 16; ++r)
            sacc[r] = __builtin_amdgcn_exp2f(sacc[r] - m);

        // pack P to f16 pairs: w_k covers j = (rr&3)+8*(rr>>2)+4*hi for rr=2k,2k+1
        unsigned w0, w1, w2, w3, w4, w5, w6, w7;
        {
            union { fp16x2 h; unsigned u; } c;
            c.h = __builtin_amdgcn_cvt_pkrtz(sacc[0],  sacc[1]);  w0 = c.u;
            c.h = __builtin_amdgcn_cvt_pkrtz(sacc[2],  sacc[3]);  w1 = c.u;
            c.h = __builtin_amdgcn_cvt_pkrtz(sacc[4],  sacc[5]);  w2 = c.u;
            c.h = __builtin_amdgcn_cvt_pkrtz(sacc[6],  sacc[7]);  w3 = c.u;
            c.h = __builtin_amdgcn_cvt_pkrtz(sacc[8],  sacc[9]);  w4 = c.u;
            c.h = __builtin_amdgcn_cvt_pkrtz(sacc[10], sacc[11]); w5 = c.u;
            c.h = __builtin_amdgcn_cvt_pkrtz(sacc[12], sacc[13]); w6 = c.u;
            c.h = __builtin_amdgcn_cvt_pkrtz(sacc[14], sacc[15]); w7 = c.u;
        }
        // in-register half-swap: builds B-frag words for both lane-halves
        unsigned A0 = w0, A2 = w2, A1 = w1, A3 = w3;
        unsigned B0 = w4, B2 = w6, B1 = w5, B3 = w7;
        asm("v_permlane32_swap_b32 %0, %1" : "+v"(A0), "+v"(A2));
        asm("v_permlane32_swap_b32 %0, %1" : "+v"(A1), "+v"(A3));
        asm("v_permlane32_swap_b32 %0, %1" : "+v"(B0), "+v"(B2));
        asm("v_permlane32_swap_b32 %0, %1" : "+v"(B1), "+v"(B3));
        union { unsigned u[4]; f16x8 v; } pf0u, pf1u;
        pf0u.u[0] = A0; pf0u.u[1] = A1; pf0u.u[2] = A2; pf0u.u[3] = A3;
        pf1u.u[0] = B0; pf1u.u[1] = B1; pf1u.u[2] = B2; pf1u.u[3] = B3;

        __builtin_amdgcn_s_setprio(1);
        acc0 = __builtin_amdgcn_mfma_f32_32x32x16_f16(vf00, pf0u.v, acc0, 0, 0, 0);
        acc1 = __builtin_amdgcn_mfma_f32_32x32x16_f16(vf10, pf0u.v, acc1, 0, 0, 0);
        acc2 = __builtin_amdgcn_mfma_f32_32x32x16_f16(onesf, pf0u.v, acc2, 0, 0, 0);
        acc0 = __builtin_amdgcn_mfma_f32_32x32x16_f16(vf01, pf1u.v, acc0, 0, 0, 0);
        acc1 = __builtin_amdgcn_mfma_f32_32x32x16_f16(vf11, pf1u.v, acc1, 0, 0, 0);
        acc2 = __builtin_amdgcn_mfma_f32_32x32x16_f16(onesf, pf1u.v, acc2, 0, 0, 0);
        __builtin_amdgcn_s_setprio(0);

        if (has) {
            kf = kf_n;
            vf00 = vn00; vf01 = vn01; vf10 = vn10; vf11 = vn11;
        }
        jt = jn;
    }
#undef LOADK
#undef LOADV

    // ---- merge 8 per-wave partials (lsum comes from acc2) ----
    if (l < 32) mml[w * 32 + il] = m;     // m uniform across halves per i
    __syncthreads();
    float gm = mml[il];
    #pragma unroll
    for (int ww = 1; ww < 8; ++ww) gm = fmaxf(gm, mml[ww * 32 + il]);
    const float f = __builtin_amdgcn_exp2f(m - gm);
    if (l < 32) lsm[w * 32 + il] = acc2[0] * f;
    #pragma unroll
    for (int r = 0; r < 16; ++r) { acc0[r] *= f; acc1[r] *= f; }

    float* ob = out + (size_t)b * 64 * NSP + i0;

    // ct = 0 (c 0..31)
    #pragma unroll
    for (int r = 0; r < 16; ++r) {
        const int cl = (r & 3) + 8 * (r >> 2) + 4 * hi;
        mrg[w * 1024 + cl * 32 + il] = acc0[r];
    }
    __syncthreads();
    #pragma unroll
    for (int rep = 0; rep < 2; ++rep) {
        const int e = t + rep * 512;
        const int c = e >> 5, i = e & 31;
        float sv = 0.0f, lg = 0.0f;
        #pragma unroll
        for (int ww = 0; ww < 8; ++ww) {
            sv += mrg[ww * 1024 + c * 32 + i];
            lg += lsm[ww * 32 + i];
        }
        float inv;
        asm("v_rcp_f32 %0, %1" : "=v"(inv) : "v"(lg));
        ob[(size_t)c * NSP + i] = sv * inv;
    }
    __syncthreads();                      // protect mrg for ct=1 overwrite

    // ct = 1 (c 32..63)
    #pragma unroll
    for (int r = 0; r < 16; ++r) {
        const int cl = (r & 3) + 8 * (r >> 2) + 4 * hi;
        mrg[w * 1024 + cl * 32 + il] = acc1[r];
    }
    __syncthreads();
    #pragma unroll
    for (int rep = 0; rep < 2; ++rep) {
        const int e = t + rep * 512;
        const int c = e >> 5, i = e & 31;
        float sv = 0.0f, lg = 0.0f;
        #pragma unroll
        for (int ww = 0; ww < 8; ++ww) {
            sv += mrg[ww * 1024 + c * 32 + i];
            lg += lsm[ww * 32 + i];
        }
        float inv;
        asm("v_rcp_f32 %0, %1" : "=v"(inv) : "v"(lg));
        ob[(size_t)(32 + c) * NSP + i] = sv * inv;
    }
}

// ---------------------------------------------------------------------------
extern "C" void kernel_launch(void* const* d_in, const int* in_sizes, int n_in,
                              void* d_out, int out_size, void* d_ws, size_t ws_size,
                              hipStream_t stream) {
    const float* x  = (const float*)d_in[0];
    const float* wq = (const float*)d_in[1];
    const float* bq = (const float*)d_in[2];
    const float* wk = (const float*)d_in[3];
    const float* bk = (const float*)d_in[4];
    const float* wv = (const float*)d_in[5];
    const float* bv = (const float*)d_in[6];
    float* out = (float*)d_out;

    ushort*   wtap = (ushort*)d_ws;                           //       0 .. 276,480
    ushort*   xpad = (ushort*)((char*)d_ws + 278528);         // 2,725,888 B
    _Float16* Qt   = (_Float16*)((char*)d_ws + 3004416);      //   256,000 B [b][s][8c]
    _Float16* Kt   = (_Float16*)((char*)d_ws + 3260416);      //   256,000 B [b][s][8c]
    _Float16* VT   = (_Float16*)((char*)d_ws + 3516416);      // 2,048,000 B [b][j/16][c][j%16]

    prep_kernel<<<dim3(3128), 64, 0, stream>>>(wq, wk, wv, x, wtap, xpad);
    conv_mfma_kernel<<<dim3(125, 2), 512, 0, stream>>>(xpad, wtap, bq, bk, bv, Qt, Kt, VT);
    attn_kernel<<<dim3(250, 2), 512, 0, stream>>>(Qt, Kt, VT, out);
}

// Round 12
// 135.232 us; speedup vs baseline: 1.2311x; 1.0580x over previous
//
#include <hip/hip_runtime.h>
#include <hip/hip_bf16.h>
#include <math.h>

#define NSP 8000      // 20*20*20 spatial
#define CIN 64
#define LOG2E 1.4426950408889634f

typedef __attribute__((ext_vector_type(8)))  short    bf16x8;
typedef __attribute__((ext_vector_type(4)))  float    f32x4;
typedef __attribute__((ext_vector_type(16))) float    f32x16;
typedef __attribute__((ext_vector_type(8)))  _Float16 f16x8;
typedef __attribute__((ext_vector_type(2)))  __fp16   fp16x2;

__device__ __forceinline__ ushort f2bf(float f) {
    unsigned u = __float_as_uint(f);
    unsigned r = (u + 0x7fffu + ((u >> 16) & 1u)) >> 16;   // RNE
    return (ushort)r;
}

// ---------------------------------------------------------------------------
// Fused prep: blocks 0..2159 build wtap[tap][co80][ci64]; blocks 2160..3127
// build xpad[b][22][22][22][ci64] (zero halo; holds x[zp-1][yp-1][xp-1]).
// ---------------------------------------------------------------------------
__global__ __launch_bounds__(64) void prep_kernel(
    const float* __restrict__ wq, const float* __restrict__ wk,
    const float* __restrict__ wv, const float* __restrict__ x,
    ushort* __restrict__ wtap, ushort* __restrict__ xpad)
{
    const int bid = blockIdx.x;
    if (bid < 2160) {
        const int tap = bid / 80;
        const int co  = bid % 80;
        const int ci  = threadIdx.x;
        float v;
        if (co < 8)       v = wq[(co * 64 + ci) * 27 + tap];
        else if (co < 16) v = wk[((co - 8) * 64 + ci) * 27 + tap];
        else              v = wv[((co - 16) * 64 + ci) * 27 + tap];
        wtap[((size_t)tap * 80 + co) * 64 + ci] = f2bf(v);
    } else {
        const int bx  = bid - 2160;        // 0..967
        const int b   = bx / 484;
        const int rem = bx % 484;
        const int zp  = rem / 22, yp = rem % 22;
        const int ci  = threadIdx.x;
        const bool zy = (zp >= 1 && zp <= 20) && (yp >= 1 && yp <= 20);
        const float* xb = x + ((size_t)b * 64 + ci) * NSP + (zp - 1) * 400 + (yp - 1) * 20;
        ushort* op = xpad + (size_t)b * 681472 + (size_t)(zp * 484 + yp * 22) * 64 + ci;
        #pragma unroll
        for (int xp = 0; xp < 22; ++xp) {
            float v = 0.0f;
            if (zy && xp >= 1 && xp <= 20) v = xb[xp - 1];
            op[xp * 64] = f2bf(v);
        }
    }
}

// ---------------------------------------------------------------------------
// Conv tap-shift implicit GEMM. 4 waves/block = 1 x 64-s tile x 4 tap-splits.
// Each wave: 64 s (4 MFMA sub-tiles sharing every A-frag), taps 7/7/7/6.
// Per tap: 10 A-loads + 8 B-loads -> 40 MFMA (A-reuse x4, no intra-block dup).
// f32 combine via conflict-free LDS [sp][sub][ct][lane][4] (61.4 KB).
// ---------------------------------------------------------------------------
__global__ __launch_bounds__(256) void conv_mfma_kernel(
    const ushort* __restrict__ xpad, const ushort* __restrict__ wtap,
    const float* __restrict__ bq, const float* __restrict__ bk,
    const float* __restrict__ bv,
    _Float16* __restrict__ Qt, _Float16* __restrict__ Kt, _Float16* __restrict__ VT)
{
    const int t  = threadIdx.x;
    const int l  = t & 63;
    const int sp = t >> 6;              // tap-split 0..3
    const int b  = blockIdx.y;
    const int s0 = blockIdx.x * 64;
    const int kq = (l >> 4) * 8;        // k-subgroup within 32

    const ushort* xpb = xpad + (size_t)b * 681472;
    const ushort* xb0; const ushort* xb1; const ushort* xb2; const ushort* xb3;
    {
        const int s = s0 + (l & 15);
        #define MKBASE(PTR, SS) { const int s_ = (SS);                       \
            const int z_ = s_ / 400, r_ = s_ % 400, y_ = r_ / 20, x_ = r_ % 20; \
            PTR = xpb + (size_t)(z_ * 484 + y_ * 22 + x_) * 64 + kq; }
        MKBASE(xb0, s);
        MKBASE(xb1, s + 16);
        MKBASE(xb2, s + 32);
        MKBASE(xb3, s + 48);
        #undef MKBASE
    }
    const ushort* wl = wtap + (l & 15) * 64 + kq;

    f32x4 acc0[5], acc1[5], acc2[5], acc3[5];
    #pragma unroll
    for (int ct = 0; ct < 5; ++ct) {
        acc0[ct] = (f32x4)0.0f; acc1[ct] = (f32x4)0.0f;
        acc2[ct] = (f32x4)0.0f; acc3[ct] = (f32x4)0.0f;
    }

#define TAP(TAPI) {                                                          \
        const int tap_ = (TAPI);                                             \
        const int dz_ = tap_ / 9, r9_ = tap_ % 9;                            \
        const int off_ = (dz_ * 484 + (r9_ / 3) * 22 + (r9_ % 3)) * 64;      \
        const bf16x8 b00 = *(const bf16x8*)(xb0 + off_);                     \
        const bf16x8 b01 = *(const bf16x8*)(xb0 + off_ + 32);                \
        const bf16x8 b10 = *(const bf16x8*)(xb1 + off_);                     \
        const bf16x8 b11 = *(const bf16x8*)(xb1 + off_ + 32);                \
        const bf16x8 b20 = *(const bf16x8*)(xb2 + off_);                     \
        const bf16x8 b21 = *(const bf16x8*)(xb2 + off_ + 32);                \
        const bf16x8 b30 = *(const bf16x8*)(xb3 + off_);                     \
        const bf16x8 b31 = *(const bf16x8*)(xb3 + off_ + 32);                \
        const ushort* wp_ = wl + (size_t)tap_ * 80 * 64;                     \
        _Pragma("unroll") for (int ct = 0; ct < 5; ++ct) {                   \
            const bf16x8 a0 = *(const bf16x8*)(wp_ + ct * 16 * 64);          \
            const bf16x8 a1 = *(const bf16x8*)(wp_ + ct * 16 * 64 + 32);     \
            acc0[ct] = __builtin_amdgcn_mfma_f32_16x16x32_bf16(a0, b00, acc0[ct], 0, 0, 0); \
            acc0[ct] = __builtin_amdgcn_mfma_f32_16x16x32_bf16(a1, b01, acc0[ct], 0, 0, 0); \
            acc1[ct] = __builtin_amdgcn_mfma_f32_16x16x32_bf16(a0, b10, acc1[ct], 0, 0, 0); \
            acc1[ct] = __builtin_amdgcn_mfma_f32_16x16x32_bf16(a1, b11, acc1[ct], 0, 0, 0); \
            acc2[ct] = __builtin_amdgcn_mfma_f32_16x16x32_bf16(a0, b20, acc2[ct], 0, 0, 0); \
            acc2[ct] = __builtin_amdgcn_mfma_f32_16x16x32_bf16(a1, b21, acc2[ct], 0, 0, 0); \
            acc3[ct] = __builtin_amdgcn_mfma_f32_16x16x32_bf16(a0, b30, acc3[ct], 0, 0, 0); \
            acc3[ct] = __builtin_amdgcn_mfma_f32_16x16x32_bf16(a1, b31, acc3[ct], 0, 0, 0); \
        } }

    if (sp == 0) {
        #pragma unroll
        for (int k = 0; k < 7; ++k) TAP(k);
    } else if (sp == 1) {
        #pragma unroll
        for (int k = 0; k < 7; ++k) TAP(7 + k);
    } else if (sp == 2) {
        #pragma unroll
        for (int k = 0; k < 7; ++k) TAP(14 + k);
    } else {
        #pragma unroll
        for (int k = 0; k < 6; ++k) TAP(21 + k);
    }
#undef TAP

    // combine the four tap-splits via LDS: [sp-1][sub][ct][lane][4] f32
    __shared__ float lacc[3][4][5][64][4];
    if (sp > 0) {
        #pragma unroll
        for (int ct = 0; ct < 5; ++ct) {
            *(f32x4*)&lacc[sp - 1][0][ct][l][0] = acc0[ct];
            *(f32x4*)&lacc[sp - 1][1][ct][l][0] = acc1[ct];
            *(f32x4*)&lacc[sp - 1][2][ct][l][0] = acc2[ct];
            *(f32x4*)&lacc[sp - 1][3][ct][l][0] = acc3[ct];
        }
    }
    __syncthreads();
    if (sp == 0) {
        #pragma unroll
        for (int sub = 0; sub < 4; ++sub) {
            const int s  = s0 + sub * 16 + (l & 15);
            const int jb = s >> 4;
            #pragma unroll
            for (int ct = 0; ct < 5; ++ct) {
                const f32x4 base = (sub == 0) ? acc0[ct] : (sub == 1) ? acc1[ct]
                                 : (sub == 2) ? acc2[ct] : acc3[ct];
                #pragma unroll
                for (int r = 0; r < 4; ++r) {
                    float v = base[r] + lacc[0][sub][ct][l][r]
                            + lacc[1][sub][ct][l][r] + lacc[2][sub][ct][l][r];
                    const int co = ct * 16 + (l >> 4) * 4 + r;
                    if (co < 8)
                        Qt[((size_t)b * NSP + s) * 8 + co] = (_Float16)((v + bq[co]) * LOG2E);
                    else if (co < 16)
                        Kt[((size_t)b * NSP + s) * 8 + (co - 8)] = (_Float16)(v + bk[co - 8]);
                    else {
                        const int c = co - 16;
                        VT[(size_t)b * 512000 + ((size_t)jb * 64 + c) * 16 + (l & 15)] =
                            (_Float16)(v + bv[c]);
                    }
                }
            }
        }
    }
}

// ---------------------------------------------------------------------------
// Barrier-free split-j flash attention (8 independent waves, i-tile 32).
// Round-10 measured-best form: permlane P-redistribution, VALU sum tree,
// per-half lsum, defer-max with in-branch shfl.
// ---------------------------------------------------------------------------
__global__ __launch_bounds__(512, 2) void attn_kernel(
    const _Float16* __restrict__ Qt, const _Float16* __restrict__ Kt,
    const _Float16* __restrict__ VT, float* __restrict__ out)
{
    const int t  = threadIdx.x;
    const int l  = t & 63;
    const int w  = t >> 6;          // j-split 0..7
    const int b  = blockIdx.y;
    const int i0 = blockIdx.x * 32;
    const int il = l & 31;
    const int hi = l >> 5;

    const _Float16* Qtb = Qt + (size_t)b * NSP * 8;
    const _Float16* Ktb = Kt + (size_t)b * NSP * 8;
    const _Float16* VTb = VT + (size_t)b * 512000;

    __shared__ __align__(16) char smem[34816];
    float* mrg = (float*)smem;              // [8][32][32] f32
    float* mml = (float*)(smem + 32768);    // [8][32]
    float* lsm = (float*)(smem + 33792);    // [8][32]

    f16x8 qf = (f16x8)(_Float16)0.0f;
    if (l < 32) qf = *(const f16x8*)&Qtb[(size_t)(i0 + il) * 8];

    float m = -INFINITY, lsum = 0.0f;       // per (i, half)
    f32x16 acc0 = (f32x16)0.0f, acc1 = (f32x16)0.0f;
    const f32x16 zero16 = (f32x16)0.0f;

#define LOADK(JT, KF) { KF = (f16x8)(_Float16)0.0f;                         \
        if (l < 32) KF = *(const f16x8*)&Ktb[(size_t)((JT) * 32 + il) * 8]; }
#define LOADV(JT, VF) { const int jb = (JT) * 2;                            \
        VF##00 = *(const f16x8*)&VTb[((size_t)(jb + 0) * 64 + il) * 16 + 8 * hi];      \
        VF##01 = *(const f16x8*)&VTb[((size_t)(jb + 1) * 64 + il) * 16 + 8 * hi];      \
        VF##10 = *(const f16x8*)&VTb[((size_t)(jb + 0) * 64 + 32 + il) * 16 + 8 * hi]; \
        VF##11 = *(const f16x8*)&VTb[((size_t)(jb + 1) * 64 + 32 + il) * 16 + 8 * hi]; }

    int jt = w;
    f16x8 kf, vf00, vf01, vf10, vf11;
    LOADK(jt, kf);
    LOADV(jt, vf);

    while (jt < 250) {
        const int jn = jt + 8;
        const bool has = (jn < 250);
        f16x8 kf_n, vn00, vn01, vn10, vn11;
        if (has) { LOADK(jn, kf_n); LOADV(jn, vn); }

        f32x16 sacc = __builtin_amdgcn_mfma_f32_32x32x16_f16(kf, qf, zero16, 0, 0, 0);

        float x0 = fmaxf(sacc[0], sacc[1]),   x1 = fmaxf(sacc[2], sacc[3]);
        float x2 = fmaxf(sacc[4], sacc[5]),   x3 = fmaxf(sacc[6], sacc[7]);
        float x4 = fmaxf(sacc[8], sacc[9]),   x5 = fmaxf(sacc[10], sacc[11]);
        float x6 = fmaxf(sacc[12], sacc[13]), x7 = fmaxf(sacc[14], sacc[15]);
        float pm = fmaxf(fmaxf(fmaxf(x0, x1), fmaxf(x2, x3)),
                         fmaxf(fmaxf(x4, x5), fmaxf(x6, x7)));

        if (__any(pm > m + 8.0f)) {
            pm = fmaxf(pm, __shfl_xor(pm, 32));
            const float mn = fmaxf(m, pm);
            const float sc = __builtin_amdgcn_exp2f(m - mn);
            #pragma unroll
            for (int r = 0; r < 16; ++r) { acc0[r] *= sc; acc1[r] *= sc; }
            lsum *= sc;
            m = mn;
        }

        #pragma unroll
        for (int r = 0; r < 16; ++r)
            sacc[r] = __builtin_amdgcn_exp2f(sacc[r] - m);
        {
            float s0 = (sacc[0] + sacc[1]) + (sacc[2] + sacc[3]);
            float s1 = (sacc[4] + sacc[5]) + (sacc[6] + sacc[7]);
            float s2 = (sacc[8] + sacc[9]) + (sacc[10] + sacc[11]);
            float s3 = (sacc[12] + sacc[13]) + (sacc[14] + sacc[15]);
            lsum += (s0 + s1) + (s2 + s3);
        }

        unsigned w0, w1, w2, w3, w4, w5, w6, w7;
        {
            union { fp16x2 h; unsigned u; } c;
            c.h = __builtin_amdgcn_cvt_pkrtz(sacc[0],  sacc[1]);  w0 = c.u;
            c.h = __builtin_amdgcn_cvt_pkrtz(sacc[2],  sacc[3]);  w1 = c.u;
            c.h = __builtin_amdgcn_cvt_pkrtz(sacc[4],  sacc[5]);  w2 = c.u;
            c.h = __builtin_amdgcn_cvt_pkrtz(sacc[6],  sacc[7]);  w3 = c.u;
            c.h = __builtin_amdgcn_cvt_pkrtz(sacc[8],  sacc[9]);  w4 = c.u;
            c.h = __builtin_amdgcn_cvt_pkrtz(sacc[10], sacc[11]); w5 = c.u;
            c.h = __builtin_amdgcn_cvt_pkrtz(sacc[12], sacc[13]); w6 = c.u;
            c.h = __builtin_amdgcn_cvt_pkrtz(sacc[14], sacc[15]); w7 = c.u;
        }
        unsigned A0 = w0, A2 = w2, A1 = w1, A3 = w3;
        unsigned B0 = w4, B2 = w6, B1 = w5, B3 = w7;
        asm("v_permlane32_swap_b32 %0, %1" : "+v"(A0), "+v"(A2));
        asm("v_permlane32_swap_b32 %0, %1" : "+v"(A1), "+v"(A3));
        asm("v_permlane32_swap_b32 %0, %1" : "+v"(B0), "+v"(B2));
        asm("v_permlane32_swap_b32 %0, %1" : "+v"(B1), "+v"(B3));
        union { unsigned u[4]; f16x8 v; } pf0u, pf1u;
        pf0u.u[0] = A0; pf0u.u[1] = A1; pf0u.u[2] = A2; pf0u.u[3] = A3;
        pf1u.u[0] = B0; pf1u.u[1] = B1; pf1u.u[2] = B2; pf1u.u[3] = B3;

        __builtin_amdgcn_s_setprio(1);
        acc0 = __builtin_amdgcn_mfma_f32_32x32x16_f16(vf00, pf0u.v, acc0, 0, 0, 0);
        acc1 = __builtin_amdgcn_mfma_f32_32x32x16_f16(vf10, pf0u.v, acc1, 0, 0, 0);
        acc0 = __builtin_amdgcn_mfma_f32_32x32x16_f16(vf01, pf1u.v, acc0, 0, 0, 0);
        acc1 = __builtin_amdgcn_mfma_f32_32x32x16_f16(vf11, pf1u.v, acc1, 0, 0, 0);
        __builtin_amdgcn_s_setprio(0);

        if (has) {
            kf = kf_n;
            vf00 = vn00; vf01 = vn01; vf10 = vn10; vf11 = vn11;
        }
        jt = jn;
    }
#undef LOADK
#undef LOADV

    lsum += __shfl_xor(lsum, 32);
    if (l < 32) mml[w * 32 + il] = m;
    __syncthreads();
    float gm = mml[il];
    #pragma unroll
    for (int ww = 1; ww < 8; ++ww) gm = fmaxf(gm, mml[ww * 32 + il]);
    const float f = __builtin_amdgcn_exp2f(m - gm);
    if (l < 32) lsm[w * 32 + il] = lsum * f;
    #pragma unroll
    for (int r = 0; r < 16; ++r) { acc0[r] *= f; acc1[r] *= f; }

    float* ob = out + (size_t)b * 64 * NSP + i0;

    #pragma unroll
    for (int r = 0; r < 16; ++r) {
        const int cl = (r & 3) + 8 * (r >> 2) + 4 * hi;
        mrg[w * 1024 + cl * 32 + il] = acc0[r];
    }
    __syncthreads();
    #pragma unroll
    for (int rep = 0; rep < 2; ++rep) {
        const int e = t + rep * 512;
        const int c = e >> 5, i = e & 31;
        float sv = 0.0f, lg = 0.0f;
        #pragma unroll
        for (int ww = 0; ww < 8; ++ww) {
            sv += mrg[ww * 1024 + c * 32 + i];
            lg += lsm[ww * 32 + i];
        }
        float inv;
        asm("v_rcp_f32 %0, %1" : "=v"(inv) : "v"(lg));
        ob[(size_t)c * NSP + i] = sv * inv;
    }
    __syncthreads();

    #pragma unroll
    for (int r = 0; r < 16; ++r) {
        const int cl = (r & 3) + 8 * (r >> 2) + 4 * hi;
        mrg[w * 1024 + cl * 32 + il] = acc1[r];
    }
    __syncthreads();
    #pragma unroll
    for (int rep = 0; rep < 2; ++rep) {
        const int e = t + rep * 512;
        const int c = e >> 5, i = e & 31;
        float sv = 0.0f, lg = 0.0f;
        #pragma unroll
        for (int ww = 0; ww < 8; ++ww) {
            sv += mrg[ww * 1024 + c * 32 + i];
            lg += lsm[ww * 32 + i];
        }
        float inv;
        asm("v_rcp_f32 %0, %1" : "=v"(inv) : "v"(lg));
        ob[(size_t)(32 + c) * NSP + i] = sv * inv;
    }
}

// ---------------------------------------------------------------------------
extern "C" void kernel_launch(void* const* d_in, const int* in_sizes, int n_in,
                              void* d_out, int out_size, void* d_ws, size_t ws_size,
                              hipStream_t stream) {
    const float* x  = (const float*)d_in[0];
    const float* wq = (const float*)d_in[1];
    const float* bq = (const float*)d_in[2];
    const float* wk = (const float*)d_in[3];
    const float* bk = (const float*)d_in[4];
    const float* wv = (const float*)d_in[5];
    const float* bv = (const float*)d_in[6];
    float* out = (float*)d_out;

    ushort*   wtap = (ushort*)d_ws;                           //       0 .. 276,480
    ushort*   xpad = (ushort*)((char*)d_ws + 278528);         // 2,725,888 B
    _Float16* Qt   = (_Float16*)((char*)d_ws + 3004416);      //   256,000 B [b][s][8c]
    _Float16* Kt   = (_Float16*)((char*)d_ws + 3260416);      //   256,000 B [b][s][8c]
    _Float16* VT   = (_Float16*)((char*)d_ws + 3516416);      // 2,048,000 B [b][j/16][c][j%16]

    prep_kernel<<<dim3(3128), 64, 0, stream>>>(wq, wk, wv, x, wtap, xpad);
    conv_mfma_kernel<<<dim3(125, 2), 256, 0, stream>>>(xpad, wtap, bq, bk, bv, Qt, Kt, VT);
    attn_kernel<<<dim3(250, 2), 512, 0, stream>>>(Qt, Kt, VT, out);
}

// Round 13
// 130.999 us; speedup vs baseline: 1.2709x; 1.0323x over previous
//
#include <hip/hip_runtime.h>
#include <hip/hip_bf16.h>
#include <math.h>

#define NSP 8000      // 20*20*20 spatial
#define CIN 64
#define LOG2E 1.4426950408889634f

typedef __attribute__((ext_vector_type(8)))  short    bf16x8;
typedef __attribute__((ext_vector_type(4)))  float    f32x4;
typedef __attribute__((ext_vector_type(16))) float    f32x16;
typedef __attribute__((ext_vector_type(8)))  _Float16 f16x8;
typedef __attribute__((ext_vector_type(2)))  __fp16   fp16x2;

__device__ __forceinline__ ushort f2bf(float f) {
    unsigned u = __float_as_uint(f);
    unsigned r = (u + 0x7fffu + ((u >> 16) & 1u)) >> 16;   // RNE
    return (ushort)r;
}

__device__ __forceinline__ float max3f(float a, float b, float c) {
    return fmaxf(fmaxf(a, b), c);     // clang fuses to v_max3_f32
}

// ---------------------------------------------------------------------------
// Fused prep: blocks 0..2159 build wtap[tap][co80][ci64]; blocks 2160..3127
// build xpad[b][22][22][22][ci64] (zero halo; holds x[zp-1][yp-1][xp-1]).
// ---------------------------------------------------------------------------
__global__ __launch_bounds__(64) void prep_kernel(
    const float* __restrict__ wq, const float* __restrict__ wk,
    const float* __restrict__ wv, const float* __restrict__ x,
    ushort* __restrict__ wtap, ushort* __restrict__ xpad)
{
    const int bid = blockIdx.x;
    if (bid < 2160) {
        const int tap = bid / 80;
        const int co  = bid % 80;
        const int ci  = threadIdx.x;
        float v;
        if (co < 8)       v = wq[(co * 64 + ci) * 27 + tap];
        else if (co < 16) v = wk[((co - 8) * 64 + ci) * 27 + tap];
        else              v = wv[((co - 16) * 64 + ci) * 27 + tap];
        wtap[((size_t)tap * 80 + co) * 64 + ci] = f2bf(v);
    } else {
        const int bx  = bid - 2160;        // 0..967
        const int b   = bx / 484;
        const int rem = bx % 484;
        const int zp  = rem / 22, yp = rem % 22;
        const int ci  = threadIdx.x;
        const bool zy = (zp >= 1 && zp <= 20) && (yp >= 1 && yp <= 20);
        const float* xb = x + ((size_t)b * 64 + ci) * NSP + (zp - 1) * 400 + (yp - 1) * 20;
        ushort* op = xpad + (size_t)b * 681472 + (size_t)(zp * 484 + yp * 22) * 64 + ci;
        #pragma unroll
        for (int xp = 0; xp < 22; ++xp) {
            float v = 0.0f;
            if (zy && xp >= 1 && xp <= 20) v = xb[xp - 1];
            op[xp * 64] = f2bf(v);
        }
    }
}

// ---------------------------------------------------------------------------
// Conv tap-shift implicit GEMM (round-12 measured best, unchanged).
// 4 waves/block = 1 x 64-s tile x 4 tap-splits; A-reuse x4.
// ---------------------------------------------------------------------------
__global__ __launch_bounds__(256) void conv_mfma_kernel(
    const ushort* __restrict__ xpad, const ushort* __restrict__ wtap,
    const float* __restrict__ bq, const float* __restrict__ bk,
    const float* __restrict__ bv,
    _Float16* __restrict__ Qt, _Float16* __restrict__ Kt, _Float16* __restrict__ VT)
{
    const int t  = threadIdx.x;
    const int l  = t & 63;
    const int sp = t >> 6;              // tap-split 0..3
    const int b  = blockIdx.y;
    const int s0 = blockIdx.x * 64;
    const int kq = (l >> 4) * 8;        // k-subgroup within 32

    const ushort* xpb = xpad + (size_t)b * 681472;
    const ushort* xb0; const ushort* xb1; const ushort* xb2; const ushort* xb3;
    {
        const int s = s0 + (l & 15);
        #define MKBASE(PTR, SS) { const int s_ = (SS);                       \
            const int z_ = s_ / 400, r_ = s_ % 400, y_ = r_ / 20, x_ = r_ % 20; \
            PTR = xpb + (size_t)(z_ * 484 + y_ * 22 + x_) * 64 + kq; }
        MKBASE(xb0, s);
        MKBASE(xb1, s + 16);
        MKBASE(xb2, s + 32);
        MKBASE(xb3, s + 48);
        #undef MKBASE
    }
    const ushort* wl = wtap + (l & 15) * 64 + kq;

    f32x4 acc0[5], acc1[5], acc2[5], acc3[5];
    #pragma unroll
    for (int ct = 0; ct < 5; ++ct) {
        acc0[ct] = (f32x4)0.0f; acc1[ct] = (f32x4)0.0f;
        acc2[ct] = (f32x4)0.0f; acc3[ct] = (f32x4)0.0f;
    }

#define TAP(TAPI) {                                                          \
        const int tap_ = (TAPI);                                             \
        const int dz_ = tap_ / 9, r9_ = tap_ % 9;                            \
        const int off_ = (dz_ * 484 + (r9_ / 3) * 22 + (r9_ % 3)) * 64;      \
        const bf16x8 b00 = *(const bf16x8*)(xb0 + off_);                     \
        const bf16x8 b01 = *(const bf16x8*)(xb0 + off_ + 32);                \
        const bf16x8 b10 = *(const bf16x8*)(xb1 + off_);                     \
        const bf16x8 b11 = *(const bf16x8*)(xb1 + off_ + 32);                \
        const bf16x8 b20 = *(const bf16x8*)(xb2 + off_);                     \
        const bf16x8 b21 = *(const bf16x8*)(xb2 + off_ + 32);                \
        const bf16x8 b30 = *(const bf16x8*)(xb3 + off_);                     \
        const bf16x8 b31 = *(const bf16x8*)(xb3 + off_ + 32);                \
        const ushort* wp_ = wl + (size_t)tap_ * 80 * 64;                     \
        _Pragma("unroll") for (int ct = 0; ct < 5; ++ct) {                   \
            const bf16x8 a0 = *(const bf16x8*)(wp_ + ct * 16 * 64);          \
            const bf16x8 a1 = *(const bf16x8*)(wp_ + ct * 16 * 64 + 32);     \
            acc0[ct] = __builtin_amdgcn_mfma_f32_16x16x32_bf16(a0, b00, acc0[ct], 0, 0, 0); \
            acc0[ct] = __builtin_amdgcn_mfma_f32_16x16x32_bf16(a1, b01, acc0[ct], 0, 0, 0); \
            acc1[ct] = __builtin_amdgcn_mfma_f32_16x16x32_bf16(a0, b10, acc1[ct], 0, 0, 0); \
            acc1[ct] = __builtin_amdgcn_mfma_f32_16x16x32_bf16(a1, b11, acc1[ct], 0, 0, 0); \
            acc2[ct] = __builtin_amdgcn_mfma_f32_16x16x32_bf16(a0, b20, acc2[ct], 0, 0, 0); \
            acc2[ct] = __builtin_amdgcn_mfma_f32_16x16x32_bf16(a1, b21, acc2[ct], 0, 0, 0); \
            acc3[ct] = __builtin_amdgcn_mfma_f32_16x16x32_bf16(a0, b30, acc3[ct], 0, 0, 0); \
            acc3[ct] = __builtin_amdgcn_mfma_f32_16x16x32_bf16(a1, b31, acc3[ct], 0, 0, 0); \
        } }

    if (sp == 0) {
        #pragma unroll
        for (int k = 0; k < 7; ++k) TAP(k);
    } else if (sp == 1) {
        #pragma unroll
        for (int k = 0; k < 7; ++k) TAP(7 + k);
    } else if (sp == 2) {
        #pragma unroll
        for (int k = 0; k < 7; ++k) TAP(14 + k);
    } else {
        #pragma unroll
        for (int k = 0; k < 6; ++k) TAP(21 + k);
    }
#undef TAP

    __shared__ float lacc[3][4][5][64][4];
    if (sp > 0) {
        #pragma unroll
        for (int ct = 0; ct < 5; ++ct) {
            *(f32x4*)&lacc[sp - 1][0][ct][l][0] = acc0[ct];
            *(f32x4*)&lacc[sp - 1][1][ct][l][0] = acc1[ct];
            *(f32x4*)&lacc[sp - 1][2][ct][l][0] = acc2[ct];
            *(f32x4*)&lacc[sp - 1][3][ct][l][0] = acc3[ct];
        }
    }
    __syncthreads();
    if (sp == 0) {
        #pragma unroll
        for (int sub = 0; sub < 4; ++sub) {
            const int s  = s0 + sub * 16 + (l & 15);
            const int jb = s >> 4;
            #pragma unroll
            for (int ct = 0; ct < 5; ++ct) {
                const f32x4 base = (sub == 0) ? acc0[ct] : (sub == 1) ? acc1[ct]
                                 : (sub == 2) ? acc2[ct] : acc3[ct];
                #pragma unroll
                for (int r = 0; r < 4; ++r) {
                    float v = base[r] + lacc[0][sub][ct][l][r]
                            + lacc[1][sub][ct][l][r] + lacc[2][sub][ct][l][r];
                    const int co = ct * 16 + (l >> 4) * 4 + r;
                    if (co < 8)
                        Qt[((size_t)b * NSP + s) * 8 + co] = (_Float16)((v + bq[co]) * LOG2E);
                    else if (co < 16)
                        Kt[((size_t)b * NSP + s) * 8 + (co - 8)] = (_Float16)(v + bk[co - 8]);
                    else {
                        const int c = co - 16;
                        VT[(size_t)b * 512000 + ((size_t)jb * 64 + c) * 16 + (l & 15)] =
                            (_Float16)(v + bv[c]);
                    }
                }
            }
        }
    }
}

// ---------------------------------------------------------------------------
// Barrier-free split-j flash attention (8 independent waves, i-tile 32).
// Round-13: unroll-2 register double-buffering (no frag copies), max3 tree,
// 4 independent lsum chains. Otherwise round-10/12 measured-best form.
// ---------------------------------------------------------------------------
__global__ __launch_bounds__(512, 2) void attn_kernel(
    const _Float16* __restrict__ Qt, const _Float16* __restrict__ Kt,
    const _Float16* __restrict__ VT, float* __restrict__ out)
{
    const int t  = threadIdx.x;
    const int l  = t & 63;
    const int w  = t >> 6;          // j-split 0..7
    const int b  = blockIdx.y;
    const int i0 = blockIdx.x * 32;
    const int il = l & 31;
    const int hi = l >> 5;

    const _Float16* Qtb = Qt + (size_t)b * NSP * 8;
    const _Float16* Ktb = Kt + (size_t)b * NSP * 8;
    const _Float16* VTb = VT + (size_t)b * 512000;

    __shared__ __align__(16) char smem[34816];
    float* mrg = (float*)smem;              // [8][32][32] f32
    float* mml = (float*)(smem + 32768);    // [8][32]
    float* lsm = (float*)(smem + 33792);    // [8][32]

    f16x8 qf = (f16x8)(_Float16)0.0f;
    if (l < 32) qf = *(const f16x8*)&Qtb[(size_t)(i0 + il) * 8];

    float m = -INFINITY;
    float ls0 = 0.0f, ls1 = 0.0f, ls2 = 0.0f, ls3 = 0.0f;
    f32x16 acc0 = (f32x16)0.0f, acc1 = (f32x16)0.0f;
    const f32x16 zero16 = (f32x16)0.0f;

#define LOADK(JT, KF) { KF = (f16x8)(_Float16)0.0f;                         \
        if (l < 32) KF = *(const f16x8*)&Ktb[(size_t)((JT) * 32 + il) * 8]; }
#define LOADV4(JT, V00, V01, V10, V11) { const int jb_ = (JT) * 2;          \
        V00 = *(const f16x8*)&VTb[((size_t)(jb_ + 0) * 64 + il) * 16 + 8 * hi];      \
        V01 = *(const f16x8*)&VTb[((size_t)(jb_ + 1) * 64 + il) * 16 + 8 * hi];      \
        V10 = *(const f16x8*)&VTb[((size_t)(jb_ + 0) * 64 + 32 + il) * 16 + 8 * hi]; \
        V11 = *(const f16x8*)&VTb[((size_t)(jb_ + 1) * 64 + 32 + il) * 16 + 8 * hi]; }

#define BODY(KF, V00, V01, V10, V11) {                                       \
        f32x16 sacc = __builtin_amdgcn_mfma_f32_32x32x16_f16(KF, qf, zero16, 0, 0, 0); \
        float t0 = max3f(sacc[0],  sacc[1],  sacc[2]);                       \
        float t1 = max3f(sacc[3],  sacc[4],  sacc[5]);                       \
        float t2 = max3f(sacc[6],  sacc[7],  sacc[8]);                       \
        float t3 = max3f(sacc[9],  sacc[10], sacc[11]);                      \
        float t4 = max3f(sacc[12], sacc[13], sacc[14]);                      \
        float pm = max3f(max3f(t0, t1, t2), fmaxf(t3, t4), sacc[15]);        \
        if (__any(pm > m + 8.0f)) {                                          \
            pm = fmaxf(pm, __shfl_xor(pm, 32));                              \
            const float mn = fmaxf(m, pm);                                   \
            const float sc = __builtin_amdgcn_exp2f(m - mn);                 \
            _Pragma("unroll") for (int r = 0; r < 16; ++r) { acc0[r] *= sc; acc1[r] *= sc; } \
            ls0 *= sc; ls1 *= sc; ls2 *= sc; ls3 *= sc;                      \
            m = mn;                                                          \
        }                                                                    \
        _Pragma("unroll") for (int r = 0; r < 16; ++r)                       \
            sacc[r] = __builtin_amdgcn_exp2f(sacc[r] - m);                   \
        ls0 += (sacc[0]  + sacc[1])  + (sacc[2]  + sacc[3]);                 \
        ls1 += (sacc[4]  + sacc[5])  + (sacc[6]  + sacc[7]);                 \
        ls2 += (sacc[8]  + sacc[9])  + (sacc[10] + sacc[11]);                \
        ls3 += (sacc[12] + sacc[13]) + (sacc[14] + sacc[15]);                \
        unsigned w0, w1, w2, w3, w4, w5, w6, w7;                             \
        {                                                                    \
            union { fp16x2 h; unsigned u; } c_;                              \
            c_.h = __builtin_amdgcn_cvt_pkrtz(sacc[0],  sacc[1]);  w0 = c_.u; \
            c_.h = __builtin_amdgcn_cvt_pkrtz(sacc[2],  sacc[3]);  w1 = c_.u; \
            c_.h = __builtin_amdgcn_cvt_pkrtz(sacc[4],  sacc[5]);  w2 = c_.u; \
            c_.h = __builtin_amdgcn_cvt_pkrtz(sacc[6],  sacc[7]);  w3 = c_.u; \
            c_.h = __builtin_amdgcn_cvt_pkrtz(sacc[8],  sacc[9]);  w4 = c_.u; \
            c_.h = __builtin_amdgcn_cvt_pkrtz(sacc[10], sacc[11]); w5 = c_.u; \
            c_.h = __builtin_amdgcn_cvt_pkrtz(sacc[12], sacc[13]); w6 = c_.u; \
            c_.h = __builtin_amdgcn_cvt_pkrtz(sacc[14], sacc[15]); w7 = c_.u; \
        }                                                                    \
        unsigned A0 = w0, A2 = w2, A1 = w1, A3 = w3;                         \
        unsigned B0 = w4, B2 = w6, B1 = w5, B3 = w7;                         \
        asm("v_permlane32_swap_b32 %0, %1" : "+v"(A0), "+v"(A2));            \
        asm("v_permlane32_swap_b32 %0, %1" : "+v"(A1), "+v"(A3));            \
        asm("v_permlane32_swap_b32 %0, %1" : "+v"(B0), "+v"(B2));            \
        asm("v_permlane32_swap_b32 %0, %1" : "+v"(B1), "+v"(B3));            \
        union { unsigned u[4]; f16x8 v; } pf0u, pf1u;                        \
        pf0u.u[0] = A0; pf0u.u[1] = A1; pf0u.u[2] = A2; pf0u.u[3] = A3;      \
        pf1u.u[0] = B0; pf1u.u[1] = B1; pf1u.u[2] = B2; pf1u.u[3] = B3;      \
        __builtin_amdgcn_s_setprio(1);                                       \
        acc0 = __builtin_amdgcn_mfma_f32_32x32x16_f16(V00, pf0u.v, acc0, 0, 0, 0); \
        acc1 = __builtin_amdgcn_mfma_f32_32x32x16_f16(V10, pf0u.v, acc1, 0, 0, 0); \
        acc0 = __builtin_amdgcn_mfma_f32_32x32x16_f16(V01, pf1u.v, acc0, 0, 0, 0); \
        acc1 = __builtin_amdgcn_mfma_f32_32x32x16_f16(V11, pf1u.v, acc1, 0, 0, 0); \
        __builtin_amdgcn_s_setprio(0);                                       \
    }

    // 250 j-tiles round-robin: wave w owns tiles w+8k. All waves do k=0..30;
    // waves 0,1 additionally do k=31.
    f16x8 kfA, vA00, vA01, vA10, vA11;
    f16x8 kfB, vB00, vB01, vB10, vB11;
    LOADK(w, kfA);
    LOADV4(w, vA00, vA01, vA10, vA11);

    for (int k = 0; k < 30; k += 2) {
        const int j1 = w + (k + 1) * 8;
        LOADK(j1, kfB); LOADV4(j1, vB00, vB01, vB10, vB11);
        BODY(kfA, vA00, vA01, vA10, vA11);
        const int j2 = w + (k + 2) * 8;
        LOADK(j2, kfA); LOADV4(j2, vA00, vA01, vA10, vA11);
        BODY(kfB, vB00, vB01, vB10, vB11);
    }
    if (w < 2) {
        const int j31 = w + 248;
        LOADK(j31, kfB); LOADV4(j31, vB00, vB01, vB10, vB11);
    }
    BODY(kfA, vA00, vA01, vA10, vA11);     // tile k=30
    if (w < 2) {
        BODY(kfB, vB00, vB01, vB10, vB11); // tile k=31
    }
#undef LOADK
#undef LOADV4
#undef BODY

    // ---- merge 8 per-wave partials ----
    float lsum = (ls0 + ls1) + (ls2 + ls3);
    lsum += __shfl_xor(lsum, 32);
    if (l < 32) mml[w * 32 + il] = m;
    __syncthreads();
    float gm = mml[il];
    #pragma unroll
    for (int ww = 1; ww < 8; ++ww) gm = fmaxf(gm, mml[ww * 32 + il]);
    const float f = __builtin_amdgcn_exp2f(m - gm);
    if (l < 32) lsm[w * 32 + il] = lsum * f;
    #pragma unroll
    for (int r = 0; r < 16; ++r) { acc0[r] *= f; acc1[r] *= f; }

    float* ob = out + (size_t)b * 64 * NSP + i0;

    #pragma unroll
    for (int r = 0; r < 16; ++r) {
        const int cl = (r & 3) + 8 * (r >> 2) + 4 * hi;
        mrg[w * 1024 + cl * 32 + il] = acc0[r];
    }
    __syncthreads();
    #pragma unroll
    for (int rep = 0; rep < 2; ++rep) {
        const int e = t + rep * 512;
        const int c = e >> 5, i = e & 31;
        float sv = 0.0f, lg = 0.0f;
        #pragma unroll
        for (int ww = 0; ww < 8; ++ww) {
            sv += mrg[ww * 1024 + c * 32 + i];
            lg += lsm[ww * 32 + i];
        }
        float inv;
        asm("v_rcp_f32 %0, %1" : "=v"(inv) : "v"(lg));
        ob[(size_t)c * NSP + i] = sv * inv;
    }
    __syncthreads();

    #pragma unroll
    for (int r = 0; r < 16; ++r) {
        const int cl = (r & 3) + 8 * (r >> 2) + 4 * hi;
        mrg[w * 1024 + cl * 32 + il] = acc1[r];
    }
    __syncthreads();
    #pragma unroll
    for (int rep = 0; rep < 2; ++rep) {
        const int e = t + rep * 512;
        const int c = e >> 5, i = e & 31;
        float sv = 0.0f, lg = 0.0f;
        #pragma unroll
        for (int ww = 0; ww < 8; ++ww) {
            sv += mrg[ww * 1024 + c * 32 + i];
            lg += lsm[ww * 32 + i];
        }
        float inv;
        asm("v_rcp_f32 %0, %1" : "=v"(inv) : "v"(lg));
        ob[(size_t)(32 + c) * NSP + i] = sv * inv;
    }
}

// ---------------------------------------------------------------------------
extern "C" void kernel_launch(void* const* d_in, const int* in_sizes, int n_in,
                              void* d_out, int out_size, void* d_ws, size_t ws_size,
                              hipStream_t stream) {
    const float* x  = (const float*)d_in[0];
    const float* wq = (const float*)d_in[1];
    const float* bq = (const float*)d_in[2];
    const float* wk = (const float*)d_in[3];
    const float* bk = (const float*)d_in[4];
    const float* wv = (const float*)d_in[5];
    const float* bv = (const float*)d_in[6];
    float* out = (float*)d_out;

    ushort*   wtap = (ushort*)d_ws;                           //       0 .. 276,480
    ushort*   xpad = (ushort*)((char*)d_ws + 278528);         // 2,725,888 B
    _Float16* Qt   = (_Float16*)((char*)d_ws + 3004416);      //   256,000 B [b][s][8c]
    _Float16* Kt   = (_Float16*)((char*)d_ws + 3260416);      //   256,000 B [b][s][8c]
    _Float16* VT   = (_Float16*)((char*)d_ws + 3516416);      // 2,048,000 B [b][j/16][c][j%16]

    prep_kernel<<<dim3(3128), 64, 0, stream>>>(wq, wk, wv, x, wtap, xpad);
    conv_mfma_kernel<<<dim3(125, 2), 256, 0, stream>>>(xpad, wtap, bq, bk, bv, Qt, Kt, VT);
    attn_kernel<<<dim3(250, 2), 512, 0, stream>>>(Qt, Kt, VT, out);
}